// Round 1
// baseline (508.025 us; speedup 1.0000x reference)
//
#include <hip/hip_runtime.h>
#include <math.h>

// Shapes: B=8, N=256, NID=64, V=GH=128, PHI=256, RHO=128
#define NB 8
#define NN 256
#define DV 128
#define NBLK 512u

// Async global->LDS DMA (16 B/lane), lane-linear addressing.
typedef __attribute__((address_space(1))) const void* gas1p;
typedef __attribute__((address_space(3))) void* las3p;
static __device__ __forceinline__ void gld16(const float* g, float* l) {
    __builtin_amdgcn_global_load_lds((gas1p)g, (las3p)l, 16, 0, 0);
}

// Device-scope grid barrier. bar[0]=arrive, bar[1]=generation (zeroed per launch).
// __threadfence() emits buffer_wbl2/buffer_inv -> cross-XCD L2 coherence.
static __device__ __forceinline__ void gridbar(unsigned* bar) {
    __syncthreads();
    if (threadIdx.x == 0) {
        __threadfence();   // release: write back dirty L2 before signaling
        unsigned g = __hip_atomic_load(bar + 1, __ATOMIC_RELAXED, __HIP_MEMORY_SCOPE_AGENT);
        if (__hip_atomic_fetch_add(bar, 1u, __ATOMIC_ACQ_REL, __HIP_MEMORY_SCOPE_AGENT) == NBLK - 1u) {
            __hip_atomic_store(bar, 0u, __ATOMIC_RELAXED, __HIP_MEMORY_SCOPE_AGENT);
            __hip_atomic_fetch_add(bar + 1, 1u, __ATOMIC_RELEASE, __HIP_MEMORY_SCOPE_AGENT);
        } else {
            while (__hip_atomic_load(bar + 1, __ATOMIC_RELAXED, __HIP_MEMORY_SCOPE_AGENT) == g)
                __builtin_amdgcn_s_sleep(2);
        }
        __threadfence();   // acquire: invalidate L1/L2 so post-barrier reads are fresh
    }
    __syncthreads();
}

// ---------------------------------------------------------------------------
// One persistent kernel; 6 grid barriers replace 6 kernel boundaries.
// Grid 512 x 256, exactly 2 blocks/CU co-resident (56.4 KB LDS, VGPR<=256).
// ---------------------------------------------------------------------------
__global__ __launch_bounds__(256, 2) void k_mega(
        const float* __restrict__ A, const float* __restrict__ X,
        const float* __restrict__ hm,
        const float* __restrict__ e1w, const float* __restrict__ e1b,
        const float* __restrict__ e2w, const float* __restrict__ e2b,
        const float* __restrict__ rw0, const float* __restrict__ rr0, const float* __restrict__ rb0,
        const float* __restrict__ law0, const float* __restrict__ lab0,
        const float* __restrict__ lbw0, const float* __restrict__ lbb0,
        const float* __restrict__ rw1, const float* __restrict__ rr1, const float* __restrict__ rb1,
        const float* __restrict__ law1, const float* __restrict__ lab1,
        const float* __restrict__ lbw1, const float* __restrict__ lbb1,
        const float* __restrict__ ng, const float* __restrict__ nbt,
        const float* __restrict__ pw1, const float* __restrict__ pb1v,
        const float* __restrict__ pw2, const float* __restrict__ pb2v,
        const float* __restrict__ qw1, const float* __restrict__ qb1,
        const float* __restrict__ qw2, const float* __restrict__ qb2,
        float* __restrict__ H, float* __restrict__ H2,
        float* __restrict__ hsum, float* __restrict__ asum,
        float* __restrict__ out, unsigned* __restrict__ bar) {
    const int bid = blockIdx.x;
    const int t = threadIdx.x;
    __shared__ __align__(16) float smem[14088];   // 55.03 KB

    // ======================= stage 1: embed =======================
    {
        const int r0 = bid * 4;
        const int q = t & 31, u = t >> 5;
        float* pool = smem;            // 12288
        float* part = smem + 8192;     // [u][r][f] 4096
        float* xq   = smem + 12288;    // [k][r] 256
        float* h1q  = smem + 12544;    // [k][r] 512
        if (bid < 16) hsum[bid * 256 + t] = 0.f;   // zero hsum+asum (contiguous)
        #pragma unroll
        for (int rnd = 0; rnd < 8; ++rnd) {
            int idx = rnd * 256 + t;
            gld16(e1w + idx * 4, &pool[idx * 4]);
        }
        if (t < 64) {
            float4 v;
            v.x = X[(size_t)(r0 + 0) * 64 + t];
            v.y = X[(size_t)(r0 + 1) * 64 + t];
            v.z = X[(size_t)(r0 + 2) * 64 + t];
            v.w = X[(size_t)(r0 + 3) * 64 + t];
            *(float4*)&xq[t * 4] = v;
        }
        __syncthreads();
        {   // L1: K=64, thread covers k in [u*8, u*8+8)
            float acc[16];
            #pragma unroll
            for (int i = 0; i < 16; ++i) acc[i] = 0.f;
            #pragma unroll
            for (int kk = 0; kk < 8; ++kk) {
                int k = u * 8 + kk;
                float4 w4 = *(const float4*)&pool[k * 128 + q * 4];
                float wc[4] = {w4.x, w4.y, w4.z, w4.w};
                float4 x4 = *(const float4*)&xq[k * 4];
                float xr[4] = {x4.x, x4.y, x4.z, x4.w};
                #pragma unroll
                for (int r = 0; r < 4; ++r)
                    #pragma unroll
                    for (int c = 0; c < 4; ++c)
                        acc[r * 4 + c] = fmaf(xr[r], wc[c], acc[r * 4 + c]);
            }
            #pragma unroll
            for (int r = 0; r < 4; ++r)
                *(float4*)&part[u * 512 + r * 128 + q * 4] =
                    make_float4(acc[r*4+0], acc[r*4+1], acc[r*4+2], acc[r*4+3]);
        }
        __syncthreads();
        #pragma unroll
        for (int rnd = 0; rnd < 4; ++rnd) {
            int idx = rnd * 256 + t;
            gld16(e2w + idx * 4, &pool[idx * 4]);
        }
        if (t < 128) {
            int r = t >> 5, fq = t & 31;
            float4 s = *(const float4*)&e1b[fq * 4];
            #pragma unroll
            for (int uu = 0; uu < 8; ++uu) {
                float4 p = *(const float4*)&part[uu * 512 + r * 128 + fq * 4];
                s.x += p.x; s.y += p.y; s.z += p.z; s.w += p.w;
            }
            h1q[(fq * 4 + 0) * 4 + r] = fmaxf(s.x, 0.f);
            h1q[(fq * 4 + 1) * 4 + r] = fmaxf(s.y, 0.f);
            h1q[(fq * 4 + 2) * 4 + r] = fmaxf(s.z, 0.f);
            h1q[(fq * 4 + 3) * 4 + r] = fmaxf(s.w, 0.f);
        }
        __syncthreads();
        float a2[16];
        #pragma unroll
        for (int i = 0; i < 16; ++i) a2[i] = 0.f;
        #pragma unroll 1
        for (int kt = 0; kt < 4; ++kt) {
            const int buf = kt & 1;
            if (kt < 3) {
                #pragma unroll
                for (int rnd = 0; rnd < 4; ++rnd) {
                    int idx = rnd * 256 + t;
                    gld16(e2w + (kt + 1) * 4096 + idx * 4,
                          &pool[(buf ^ 1) * 4096 + idx * 4]);
                }
            }
            const float* wt = &pool[buf * 4096];
            #pragma unroll
            for (int kk = 0; kk < 4; ++kk) {
                int kl = u * 4 + kk;
                float4 w4 = *(const float4*)&wt[kl * 128 + q * 4];
                float wc[4] = {w4.x, w4.y, w4.z, w4.w};
                float4 h4 = *(const float4*)&h1q[(kt * 32 + kl) * 4];
                float hr[4] = {h4.x, h4.y, h4.z, h4.w};
                #pragma unroll
                for (int r = 0; r < 4; ++r)
                    #pragma unroll
                    for (int c = 0; c < 4; ++c)
                        a2[r * 4 + c] = fmaf(hr[r], wc[c], a2[r * 4 + c]);
            }
            __syncthreads();
        }
        #pragma unroll
        for (int r = 0; r < 4; ++r)
            *(float4*)&part[u * 512 + r * 128 + q * 4] =
                make_float4(a2[r*4+0], a2[r*4+1], a2[r*4+2], a2[r*4+3]);
        __syncthreads();
        if (t < 128) {
            int r = t >> 5, fq = t & 31;
            float4 s = *(const float4*)&e2b[fq * 4];
            #pragma unroll
            for (int uu = 0; uu < 8; ++uu) {
                float4 p = *(const float4*)&part[uu * 512 + r * 128 + fq * 4];
                s.x += p.x; s.y += p.y; s.z += p.z; s.w += p.w;
            }
            *(float4*)&H[(size_t)(r0 + r) * 128 + fq * 4] = s;
        }
    }
    gridbar(bar);

    // ======================= stages 2-5: 2x (gcn1, gcn2) =======================
    for (int it = 0; it < 2; ++it) {
        const float* Wrel  = it ? rw1  : rw0;
        const float* Wroot = it ? rr1  : rr0;
        const float* rbias = it ? rb1  : rb0;
        const float* law   = it ? law1 : law0;
        const float* lab   = it ? lab1 : lab0;
        const float* lbw   = it ? lbw1 : lbw0;
        const float* lbb   = it ? lbb1 : lbb0;

        // ---- gcn1: relation-mean aggregation + RGCN linear ----
        {
            const int b  = bid >> 6;
            const int j0 = (bid & 63) * 4;
            const int q = t & 31, u = t >> 5;
            float* pool = smem;            // 12288
            float* pb   = smem + 12288;    // 1536 [k][h4|m0_4|m1_4]
            float* cntp = smem + 13824;    // 256
            float* cnt  = smem + 14080;    // 8
            float* htile = pool;           // [2][4096] (phase A)
            float* maskM = pool + 8192;    // [256][8]
            float* part  = pool;           // [8][1024] (A-combine)
            const float* Ab = A + (size_t)b * 65536;
            const float* Hb = H + (size_t)b * 32768;
            const float* W0 = Wrel;
            const float* W1 = Wrel + 16384;

            #pragma unroll
            for (int rnd = 0; rnd < 4; ++rnd) {
                int idx = rnd * 256 + t;
                gld16(Hb + idx * 4, &htile[idx * 4]);
            }
            {   // masks: thread t owns row i=t
                float4 a = *(const float4*)(Ab + (size_t)t * 256 + j0);
                float4 m0, m1;
                m0.x = (a.x < 0.f) ? 1.f : 0.f; m1.x = (a.x > 0.f) ? 1.f : 0.f;
                m0.y = (a.y < 0.f) ? 1.f : 0.f; m1.y = (a.y > 0.f) ? 1.f : 0.f;
                m0.z = (a.z < 0.f) ? 1.f : 0.f; m1.z = (a.z > 0.f) ? 1.f : 0.f;
                m0.w = (a.w < 0.f) ? 1.f : 0.f; m1.w = (a.w > 0.f) ? 1.f : 0.f;
                *(float4*)&maskM[t * 8]     = m0;
                *(float4*)&maskM[t * 8 + 4] = m1;
            }
            __syncthreads();
            {   // count partials: 32 chunks x 8 slots
                int chunk = t >> 3, slot = t & 7;
                float c = 0.f;
                #pragma unroll
                for (int qq = 0; qq < 8; ++qq) c += maskM[(chunk * 8 + qq) * 8 + slot];
                cntp[slot * 32 + chunk] = c;
            }
            float acc0[16], acc1[16];
            #pragma unroll
            for (int i = 0; i < 16; ++i) { acc0[i] = 0.f; acc1[i] = 0.f; }
            #pragma unroll 1
            for (int tl = 0; tl < 8; ++tl) {
                const int buf = tl & 1;
                if (tl < 7) {
                    #pragma unroll
                    for (int rnd = 0; rnd < 4; ++rnd) {
                        int idx = rnd * 256 + t;
                        gld16(Hb + (tl + 1) * 4096 + idx * 4,
                              &htile[(buf ^ 1) * 4096 + idx * 4]);
                    }
                }
                const float* hb = &htile[buf * 4096];
                #pragma unroll
                for (int ii = 0; ii < 4; ++ii) {
                    int iL = u * 4 + ii;
                    int i  = tl * 32 + iL;
                    float4 h4 = *(const float4*)&hb[iL * 128 + q * 4];
                    float hc[4] = {h4.x, h4.y, h4.z, h4.w};
                    float4 m0 = *(const float4*)&maskM[i * 8];
                    float4 m1 = *(const float4*)&maskM[i * 8 + 4];
                    float mr0[4] = {m0.x, m0.y, m0.z, m0.w};
                    float mr1[4] = {m1.x, m1.y, m1.z, m1.w};
                    #pragma unroll
                    for (int r = 0; r < 4; ++r)
                        #pragma unroll
                        for (int c = 0; c < 4; ++c) {
                            acc0[r * 4 + c] = fmaf(mr0[r], hc[c], acc0[r * 4 + c]);
                            acc1[r * 4 + c] = fmaf(mr1[r], hc[c], acc1[r * 4 + c]);
                        }
                }
                __syncthreads();
            }
            #pragma unroll
            for (int r = 0; r < 4; ++r) {
                *(float4*)&part[u * 1024 + r * 128 + q * 4] =
                    make_float4(acc0[r*4+0], acc0[r*4+1], acc0[r*4+2], acc0[r*4+3]);
                *(float4*)&part[u * 1024 + (4 + r) * 128 + q * 4] =
                    make_float4(acc1[r*4+0], acc1[r*4+1], acc1[r*4+2], acc1[r*4+3]);
            }
            if (t < 8) {
                float s = 0.f;
                #pragma unroll
                for (int c = 0; c < 32; ++c) s += cntp[t * 32 + c];
                cnt[t] = s;
            }
            __syncthreads();
            {   // A-combine -> means into pb (slot = rel*4+r)
                int slot = t >> 5, fq = t & 31;
                float4 s = make_float4(0.f, 0.f, 0.f, 0.f);
                #pragma unroll
                for (int uu = 0; uu < 8; ++uu) {
                    float4 p = *(const float4*)&part[uu * 1024 + slot * 128 + fq * 4];
                    s.x += p.x; s.y += p.y; s.z += p.z; s.w += p.w;
                }
                float rc = 1.f / fmaxf(cnt[slot], 1.f);
                pb[(fq * 4 + 0) * 12 + 4 + slot] = s.x * rc;
                pb[(fq * 4 + 1) * 12 + 4 + slot] = s.y * rc;
                pb[(fq * 4 + 2) * 12 + 4 + slot] = s.z * rc;
                pb[(fq * 4 + 3) * 12 + 4 + slot] = s.w * rc;
            }
            if (t < 128) {  // root rows -> pb
                int r = t >> 5, fq = t & 31;
                float4 g4 = *(const float4*)(Hb + (size_t)(j0 + r) * 128 + fq * 4);
                pb[(fq * 4 + 0) * 12 + r] = g4.x;
                pb[(fq * 4 + 1) * 12 + r] = g4.y;
                pb[(fq * 4 + 2) * 12 + r] = g4.z;
                pb[(fq * 4 + 3) * 12 + r] = g4.w;
            }
            __syncthreads();
            #pragma unroll
            for (int rnd = 0; rnd < 6; ++rnd) {
                int idx = rnd * 256 + t;
                int mat = idx >> 9, rem = idx & 511;
                const float* Wm = (mat == 0) ? Wroot : ((mat == 1) ? W0 : W1);
                gld16(Wm + rem * 4, &pool[mat * 2048 + rem * 4]);
            }
            __syncthreads();
            float bcc[16];
            #pragma unroll
            for (int i = 0; i < 16; ++i) bcc[i] = 0.f;
            #pragma unroll 1
            for (int kt = 0; kt < 8; ++kt) {
                const int buf = kt & 1;
                if (kt < 7) {
                    #pragma unroll
                    for (int rnd = 0; rnd < 6; ++rnd) {
                        int idx = rnd * 256 + t;
                        int mat = idx >> 9, rem = idx & 511;
                        const float* Wm = (mat == 0) ? Wroot : ((mat == 1) ? W0 : W1);
                        gld16(Wm + (kt + 1) * 2048 + rem * 4,
                              &pool[(buf ^ 1) * 6144 + mat * 2048 + rem * 4]);
                    }
                }
                const float* wt = &pool[buf * 6144];
                #pragma unroll
                for (int kk = 0; kk < 2; ++kk) {
                    int kl = u * 2 + kk;
                    int k  = kt * 16 + kl;
                    float4 wr = *(const float4*)&wt[kl * 128 + q * 4];
                    float4 wa = *(const float4*)&wt[2048 + kl * 128 + q * 4];
                    float4 wb = *(const float4*)&wt[4096 + kl * 128 + q * 4];
                    float wrc[4] = {wr.x, wr.y, wr.z, wr.w};
                    float wac[4] = {wa.x, wa.y, wa.z, wa.w};
                    float wbc[4] = {wb.x, wb.y, wb.z, wb.w};
                    float4 hv = *(const float4*)&pb[k * 12];
                    float4 q0 = *(const float4*)&pb[k * 12 + 4];
                    float4 q1 = *(const float4*)&pb[k * 12 + 8];
                    float hr[4] = {hv.x, hv.y, hv.z, hv.w};
                    float m0r[4] = {q0.x, q0.y, q0.z, q0.w};
                    float m1r[4] = {q1.x, q1.y, q1.z, q1.w};
                    #pragma unroll
                    for (int r = 0; r < 4; ++r)
                        #pragma unroll
                        for (int c = 0; c < 4; ++c) {
                            float v = bcc[r * 4 + c];
                            v = fmaf(hr[r], wrc[c], v);
                            v = fmaf(m0r[r], wac[c], v);
                            v = fmaf(m1r[r], wbc[c], v);
                            bcc[r * 4 + c] = v;
                        }
                }
                __syncthreads();
            }
            float* bpart = pool;   // [8][4][128]
            #pragma unroll
            for (int r = 0; r < 4; ++r)
                *(float4*)&bpart[u * 512 + r * 128 + q * 4] =
                    make_float4(bcc[r*4+0], bcc[r*4+1], bcc[r*4+2], bcc[r*4+3]);
            __syncthreads();
            if (t < 128) {
                int r = t >> 5, fq = t & 31;
                float4 s = *(const float4*)&rbias[fq * 4];
                #pragma unroll
                for (int uu = 0; uu < 8; ++uu) {
                    float4 p = *(const float4*)&bpart[uu * 512 + r * 128 + fq * 4];
                    s.x += p.x; s.y += p.y; s.z += p.z; s.w += p.w;
                }
                *(float4*)&H2[(size_t)(b * 256 + j0 + r) * 128 + fq * 4] = s;
            }
        }
        gridbar(bar);

        // ---- gcn2: |A|-aggregation + LN + 2-layer MLP + H-update ----
        {
            const int b  = bid >> 6;
            const int i0 = (bid & 63) * 4;
            const int q = t & 31, u = t >> 5;
            float* pool = smem;            // 9216
            float* xq   = smem + 9216;     // [k][r] 512
            float* uq   = smem + 9728;     // [k][r] 512
            float* red  = smem + 10240;    // 16
            float* mi   = smem + 10256;    // 8
            float* tileb = pool;           // [2][4096]
            float* absA  = pool + 8192;    // [256][4]
            float* part  = pool;           // [8][4][128]
            const float* Ab  = A + (size_t)b * 65536;
            const float* H2b = H2 + (size_t)b * 32768;

            #pragma unroll
            for (int rnd = 0; rnd < 4; ++rnd) {
                int idx = rnd * 256 + t;
                gld16(H2b + idx * 4, &tileb[idx * 4]);
            }
            {
                float4 av;
                av.x = fabsf(Ab[(size_t)(i0 + 0) * 256 + t]);
                av.y = fabsf(Ab[(size_t)(i0 + 1) * 256 + t]);
                av.z = fabsf(Ab[(size_t)(i0 + 2) * 256 + t]);
                av.w = fabsf(Ab[(size_t)(i0 + 3) * 256 + t]);
                *(float4*)&absA[t * 4] = av;
            }
            __syncthreads();
            float acc[16];
            #pragma unroll
            for (int i = 0; i < 16; ++i) acc[i] = 0.f;
            #pragma unroll 1
            for (int tl = 0; tl < 8; ++tl) {
                const int buf = tl & 1;
                if (tl < 7) {
                    #pragma unroll
                    for (int rnd = 0; rnd < 4; ++rnd) {
                        int idx = rnd * 256 + t;
                        gld16(H2b + (tl + 1) * 4096 + idx * 4,
                              &tileb[(buf ^ 1) * 4096 + idx * 4]);
                    }
                }
                const float* hb = &tileb[buf * 4096];
                #pragma unroll
                for (int jj = 0; jj < 4; ++jj) {
                    int jL = u * 4 + jj;
                    int j  = tl * 32 + jL;
                    float4 h4 = *(const float4*)&hb[jL * 128 + q * 4];
                    float hc[4] = {h4.x, h4.y, h4.z, h4.w};
                    float4 a4 = *(const float4*)&absA[j * 4];
                    float ar[4] = {a4.x, a4.y, a4.z, a4.w};
                    #pragma unroll
                    for (int r = 0; r < 4; ++r)
                        #pragma unroll
                        for (int c = 0; c < 4; ++c)
                            acc[r * 4 + c] = fmaf(ar[r], hc[c], acc[r * 4 + c]);
                }
                __syncthreads();
            }
            #pragma unroll
            for (int r = 0; r < 4; ++r)
                *(float4*)&part[u * 512 + r * 128 + q * 4] =
                    make_float4(acc[r*4+0], acc[r*4+1], acc[r*4+2], acc[r*4+3]);
            __syncthreads();
            #pragma unroll
            for (int rnd = 0; rnd < 2; ++rnd) {
                int idx = rnd * 256 + t;
                gld16(law + idx * 4, &pool[4096 + idx * 4]);
            }
            float x[4] = {0.f, 0.f, 0.f, 0.f};
            if (t < 128) {
                const int wv2 = t >> 6;
                #pragma unroll
                for (int r = 0; r < 4; ++r) {
                    float s = 0.f;
                    #pragma unroll
                    for (int uu = 0; uu < 8; ++uu) s += part[uu * 512 + r * 128 + t];
                    x[r] = s;
                }
                #pragma unroll
                for (int r = 0; r < 4; ++r) {
                    float s = x[r], s2 = x[r] * x[r];
                    #pragma unroll
                    for (int o = 32; o > 0; o >>= 1) {
                        s  += __shfl_down(s, o, 64);
                        s2 += __shfl_down(s2, o, 64);
                    }
                    if ((t & 63) == 0) {
                        red[r * 4 + wv2 * 2] = s;
                        red[r * 4 + wv2 * 2 + 1] = s2;
                    }
                }
            }
            __syncthreads();
            if (t < 4) {
                float s  = red[t * 4] + red[t * 4 + 2];
                float s2 = red[t * 4 + 1] + red[t * 4 + 3];
                float m = s * (1.f / 128.f);
                float v = s2 * (1.f / 128.f) - m * m;
                mi[t * 2] = m;
                mi[t * 2 + 1] = rsqrtf(v + 1e-5f);
            }
            __syncthreads();
            if (t < 128) {
                float gf = ng[t], bf = nbt[t];
                float4 xv;
                xv.x = fmaxf((x[0] - mi[0]) * mi[1] * gf + bf, 0.f);
                xv.y = fmaxf((x[1] - mi[2]) * mi[3] * gf + bf, 0.f);
                xv.z = fmaxf((x[2] - mi[4]) * mi[5] * gf + bf, 0.f);
                xv.w = fmaxf((x[3] - mi[6]) * mi[7] * gf + bf, 0.f);
                *(float4*)&xq[t * 4] = xv;
            }
            __syncthreads();
            float u1[16];
            #pragma unroll
            for (int i = 0; i < 16; ++i) u1[i] = 0.f;
            #pragma unroll 1
            for (int kt = 0; kt < 8; ++kt) {
                const int buf = kt & 1;
                if (kt < 7) {
                    #pragma unroll
                    for (int rnd = 0; rnd < 2; ++rnd) {
                        int idx = rnd * 256 + t;
                        gld16(law + (kt + 1) * 2048 + idx * 4,
                              &pool[4096 + (buf ^ 1) * 2048 + idx * 4]);
                    }
                }
                const float* wt = &pool[4096 + buf * 2048];
                #pragma unroll
                for (int kk = 0; kk < 2; ++kk) {
                    int kl = u * 2 + kk;
                    int k  = kt * 16 + kl;
                    float4 w4 = *(const float4*)&wt[kl * 128 + q * 4];
                    float wc[4] = {w4.x, w4.y, w4.z, w4.w};
                    float4 x4 = *(const float4*)&xq[k * 4];
                    float xr[4] = {x4.x, x4.y, x4.z, x4.w};
                    #pragma unroll
                    for (int r = 0; r < 4; ++r)
                        #pragma unroll
                        for (int c = 0; c < 4; ++c)
                            u1[r * 4 + c] = fmaf(xr[r], wc[c], u1[r * 4 + c]);
                }
                __syncthreads();
            }
            #pragma unroll
            for (int r = 0; r < 4; ++r)
                *(float4*)&part[u * 512 + r * 128 + q * 4] =
                    make_float4(u1[r*4+0], u1[r*4+1], u1[r*4+2], u1[r*4+3]);
            __syncthreads();
            #pragma unroll
            for (int rnd = 0; rnd < 2; ++rnd) {
                int idx = rnd * 256 + t;
                gld16(lbw + idx * 4, &pool[4096 + idx * 4]);
            }
            if (t < 128) {
                float bb = lab[t];
                float4 uv;
                float s0 = 0.f, s1 = 0.f, s2 = 0.f, s3 = 0.f;
                #pragma unroll
                for (int uu = 0; uu < 8; ++uu) {
                    s0 += part[uu * 512 + 0 * 128 + t];
                    s1 += part[uu * 512 + 1 * 128 + t];
                    s2 += part[uu * 512 + 2 * 128 + t];
                    s3 += part[uu * 512 + 3 * 128 + t];
                }
                uv.x = fmaxf(s0 + bb, 0.f);
                uv.y = fmaxf(s1 + bb, 0.f);
                uv.z = fmaxf(s2 + bb, 0.f);
                uv.w = fmaxf(s3 + bb, 0.f);
                *(float4*)&uq[t * 4] = uv;
            }
            __syncthreads();
            float u2[16];
            #pragma unroll
            for (int i = 0; i < 16; ++i) u2[i] = 0.f;
            #pragma unroll 1
            for (int kt = 0; kt < 8; ++kt) {
                const int buf = kt & 1;
                if (kt < 7) {
                    #pragma unroll
                    for (int rnd = 0; rnd < 2; ++rnd) {
                        int idx = rnd * 256 + t;
                        gld16(lbw + (kt + 1) * 2048 + idx * 4,
                              &pool[4096 + (buf ^ 1) * 2048 + idx * 4]);
                    }
                }
                const float* wt = &pool[4096 + buf * 2048];
                #pragma unroll
                for (int kk = 0; kk < 2; ++kk) {
                    int kl = u * 2 + kk;
                    int k  = kt * 16 + kl;
                    float4 w4 = *(const float4*)&wt[kl * 128 + q * 4];
                    float wc[4] = {w4.x, w4.y, w4.z, w4.w};
                    float4 x4 = *(const float4*)&uq[k * 4];
                    float xr[4] = {x4.x, x4.y, x4.z, x4.w};
                    #pragma unroll
                    for (int r = 0; r < 4; ++r)
                        #pragma unroll
                        for (int c = 0; c < 4; ++c)
                            u2[r * 4 + c] = fmaf(xr[r], wc[c], u2[r * 4 + c]);
                }
                __syncthreads();
            }
            #pragma unroll
            for (int r = 0; r < 4; ++r)
                *(float4*)&part[u * 512 + r * 128 + q * 4] =
                    make_float4(u2[r*4+0], u2[r*4+1], u2[r*4+2], u2[r*4+3]);
            __syncthreads();
            if (t < 128) {
                int r = t >> 5, fq = t & 31;
                float4 s = *(const float4*)&lbb[fq * 4];
                #pragma unroll
                for (int uu = 0; uu < 8; ++uu) {
                    float4 p = *(const float4*)&part[uu * 512 + r * 128 + fq * 4];
                    s.x += p.x; s.y += p.y; s.z += p.z; s.w += p.w;
                }
                float4 hold = *(const float4*)(H + (size_t)(b * 256 + i0 + r) * 128 + fq * 4);
                s.x += hold.x; s.y += hold.y; s.z += hold.z; s.w += hold.w;
                *(float4*)&H[(size_t)(b * 256 + i0 + r) * 128 + fq * 4] = s;
            }
        }
        gridbar(bar);
    }

    // ======================= stage 6: deepset (4 rows/block) =======================
    {
        const int r0 = bid * 4;
        const int b  = bid >> 6;
        const int q = t & 63, u = t >> 6;
        float* wt2  = smem;            // [2][4096] : 16k x 256
        float* part = smem + 8192;     // [4 u][4 r][256]
        float* hraw = smem + 12288;    // [4 r][128]
        float* ph2  = smem + 12800;    // [4 r][256]
        float* hmv  = smem + 13824;    // 4
        #pragma unroll
        for (int rnd = 0; rnd < 4; ++rnd) {
            int idx = rnd * 256 + t;
            gld16(pw1 + idx * 4, &wt2[idx * 4]);
        }
        if (t < 128) gld16(H + (size_t)r0 * 128 + t * 4, &hraw[t * 4]);
        if (t < 4) hmv[t] = hm[r0 + t];
        __syncthreads();
        float acc[16];
        #pragma unroll
        for (int i = 0; i < 16; ++i) acc[i] = 0.f;
        #pragma unroll 1
        for (int kt = 0; kt < 8; ++kt) {     // K=128, tiles of 16 k
            const int buf = kt & 1;
            if (kt < 7) {
                #pragma unroll
                for (int rnd = 0; rnd < 4; ++rnd) {
                    int idx = rnd * 256 + t;
                    gld16(pw1 + (kt + 1) * 4096 + idx * 4, &wt2[(buf ^ 1) * 4096 + idx * 4]);
                }
            }
            const float* wt = &wt2[buf * 4096];
            #pragma unroll
            for (int kk = 0; kk < 4; ++kk) {
                int kl = u * 4 + kk;
                int k  = kt * 16 + kl;
                float4 w4 = *(const float4*)&wt[kl * 256 + q * 4];
                float wc[4] = {w4.x, w4.y, w4.z, w4.w};
                float hr[4];
                #pragma unroll
                for (int r = 0; r < 4; ++r) hr[r] = hraw[r * 128 + k];
                #pragma unroll
                for (int r = 0; r < 4; ++r)
                    #pragma unroll
                    for (int c = 0; c < 4; ++c)
                        acc[r * 4 + c] = fmaf(hr[r], wc[c], acc[r * 4 + c]);
            }
            __syncthreads();
        }
        #pragma unroll
        for (int r = 0; r < 4; ++r)
            *(float4*)&part[u * 1024 + r * 256 + q * 4] =
                make_float4(acc[r*4+0], acc[r*4+1], acc[r*4+2], acc[r*4+3]);
        __syncthreads();
        #pragma unroll
        for (int rnd = 0; rnd < 4; ++rnd) {
            int idx = rnd * 256 + t;
            gld16(pw2 + idx * 4, &wt2[idx * 4]);
        }
        {   // combine L1 -> ph2 (relu)
            int r = t >> 6, fq = t & 63;
            float4 s = *(const float4*)&pb1v[fq * 4];
            #pragma unroll
            for (int uu = 0; uu < 4; ++uu) {
                float4 p = *(const float4*)&part[uu * 1024 + r * 256 + fq * 4];
                s.x += p.x; s.y += p.y; s.z += p.z; s.w += p.w;
            }
            s.x = fmaxf(s.x, 0.f); s.y = fmaxf(s.y, 0.f);
            s.z = fmaxf(s.z, 0.f); s.w = fmaxf(s.w, 0.f);
            *(float4*)&ph2[r * 256 + fq * 4] = s;
        }
        __syncthreads();
        float a2[16];
        #pragma unroll
        for (int i = 0; i < 16; ++i) a2[i] = 0.f;
        #pragma unroll 1
        for (int kt = 0; kt < 16; ++kt) {    // K=256, tiles of 16 k
            const int buf = kt & 1;
            if (kt < 15) {
                #pragma unroll
                for (int rnd = 0; rnd < 4; ++rnd) {
                    int idx = rnd * 256 + t;
                    gld16(pw2 + (kt + 1) * 4096 + idx * 4, &wt2[(buf ^ 1) * 4096 + idx * 4]);
                }
            }
            const float* wt = &wt2[buf * 4096];
            #pragma unroll
            for (int kk = 0; kk < 4; ++kk) {
                int kl = u * 4 + kk;
                int k  = kt * 16 + kl;
                float4 w4 = *(const float4*)&wt[kl * 256 + q * 4];
                float wc[4] = {w4.x, w4.y, w4.z, w4.w};
                float pr[4];
                #pragma unroll
                for (int r = 0; r < 4; ++r) pr[r] = ph2[r * 256 + k];
                #pragma unroll
                for (int r = 0; r < 4; ++r)
                    #pragma unroll
                    for (int c = 0; c < 4; ++c)
                        a2[r * 4 + c] = fmaf(pr[r], wc[c], a2[r * 4 + c]);
            }
            __syncthreads();
        }
        #pragma unroll
        for (int r = 0; r < 4; ++r)
            *(float4*)&part[u * 1024 + r * 256 + q * 4] =
                make_float4(a2[r*4+0], a2[r*4+1], a2[r*4+2], a2[r*4+3]);
        __syncthreads();
        {   // final combine + relu + masked pool (f = t)
            float bb = pb2v[t];
            float hp = 0.f, sp = 0.f;
            #pragma unroll
            for (int r = 0; r < 4; ++r) {
                float s = bb;
                #pragma unroll
                for (int uu = 0; uu < 4; ++uu) s += part[uu * 1024 + r * 256 + t];
                float p = fmaxf(s, 0.f);
                sp += p;
                hp = fmaf(p, hmv[r], hp);
            }
            atomicAdd(&hsum[b * 256 + t], hp);
            atomicAdd(&asum[b * 256 + t], sp - hp);
        }
    }
    gridbar(bar);

    // ======================= stage 7: rho (blocks 0..7) =======================
    if (bid >= 8) return;
    {
        const int bIdx = bid;
        const int q = t & 31, u = t >> 5;
        float* pool = smem;            // 8192 dbuf + 2048 part
        float* sv   = smem + 10240;    // 512
        float* wsv  = smem + 10752;    // 2
        float* part = pool + 8192;
        #pragma unroll
        for (int rnd = 0; rnd < 4; ++rnd) {
            int idx = rnd * 256 + t;
            gld16(qw1 + idx * 4, &pool[idx * 4]);
        }
        sv[t] = hsum[bIdx * 256 + t];
        sv[256 + t] = asum[bIdx * 256 + t];
        __syncthreads();
        float aH[4] = {0.f, 0.f, 0.f, 0.f}, aA[4] = {0.f, 0.f, 0.f, 0.f};
        #pragma unroll 1
        for (int kt = 0; kt < 8; ++kt) {
            const int buf = kt & 1;
            if (kt < 7) {
                #pragma unroll
                for (int rnd = 0; rnd < 4; ++rnd) {
                    int idx = rnd * 256 + t;
                    gld16(qw1 + (kt + 1) * 4096 + idx * 4,
                          &pool[(buf ^ 1) * 4096 + idx * 4]);
                }
            }
            const float* wt = &pool[buf * 4096];
            #pragma unroll
            for (int kk = 0; kk < 4; ++kk) {
                int kl = u * 4 + kk;
                int k  = kt * 32 + kl;
                float4 w4 = *(const float4*)&wt[kl * 128 + q * 4];
                float sh = sv[k], sa = sv[256 + k];
                aH[0] = fmaf(sh, w4.x, aH[0]); aA[0] = fmaf(sa, w4.x, aA[0]);
                aH[1] = fmaf(sh, w4.y, aH[1]); aA[1] = fmaf(sa, w4.y, aA[1]);
                aH[2] = fmaf(sh, w4.z, aH[2]); aA[2] = fmaf(sa, w4.z, aA[2]);
                aH[3] = fmaf(sh, w4.w, aH[3]); aA[3] = fmaf(sa, w4.w, aA[3]);
            }
            __syncthreads();
        }
        *(float4*)&part[u * 256 + q * 4]       = make_float4(aH[0], aH[1], aH[2], aH[3]);
        *(float4*)&part[u * 256 + 128 + q * 4] = make_float4(aA[0], aA[1], aA[2], aA[3]);
        __syncthreads();
        if (t < 64) {
            int vec = t >> 5, fq = t & 31;
            float4 s = make_float4(0.f, 0.f, 0.f, 0.f);
            #pragma unroll
            for (int uu = 0; uu < 8; ++uu) {
                float4 p = *(const float4*)&part[uu * 256 + vec * 128 + fq * 4];
                s.x += p.x; s.y += p.y; s.z += p.z; s.w += p.w;
            }
            float4 bb = *(const float4*)&qb1[fq * 4];
            float4 w2q = *(const float4*)&qw2[fq * 4];
            float p = fmaxf(s.x + bb.x, 0.f) * w2q.x
                    + fmaxf(s.y + bb.y, 0.f) * w2q.y
                    + fmaxf(s.z + bb.z, 0.f) * w2q.z
                    + fmaxf(s.w + bb.w, 0.f) * w2q.w;
            #pragma unroll
            for (int o = 16; o > 0; o >>= 1) p += __shfl_down(p, o, 32);
            if ((t & 31) == 0) wsv[vec] = p;
        }
        __syncthreads();
        if (t == 0) out[bIdx] = 0.5f + 0.5f * tanhf(wsv[0] - wsv[1]);
    }
}

// ---------------------------------------------------------------------------
extern "C" void kernel_launch(void* const* d_in, const int* in_sizes, int n_in,
                              void* d_out, int out_size, void* d_ws, size_t ws_size,
                              hipStream_t stream) {
    const float* A         = (const float*)d_in[0];
    const float* X         = (const float*)d_in[1];
    const float* home_mask = (const float*)d_in[2];
    const float* emb1_w    = (const float*)d_in[3];
    const float* emb1_b    = (const float*)d_in[4];
    const float* emb2_w    = (const float*)d_in[5];
    const float* emb2_b    = (const float*)d_in[6];
    const float* rgcn_w0    = (const float*)d_in[7];
    const float* rgcn_root0 = (const float*)d_in[8];
    const float* rgcn_bias0 = (const float*)d_in[9];
    const float* lina_w0    = (const float*)d_in[10];
    const float* lina_b0    = (const float*)d_in[11];
    const float* linb_w0    = (const float*)d_in[12];
    const float* linb_b0    = (const float*)d_in[13];
    const float* rgcn_w1    = (const float*)d_in[14];
    const float* rgcn_root1 = (const float*)d_in[15];
    const float* rgcn_bias1 = (const float*)d_in[16];
    const float* lina_w1    = (const float*)d_in[17];
    const float* lina_b1    = (const float*)d_in[18];
    const float* linb_w1    = (const float*)d_in[19];
    const float* linb_b1    = (const float*)d_in[20];
    const float* norm_g  = (const float*)d_in[21];
    const float* norm_b  = (const float*)d_in[22];
    const float* phi_w1  = (const float*)d_in[23];
    const float* phi_b1  = (const float*)d_in[24];
    const float* phi_w2  = (const float*)d_in[25];
    const float* phi_b2  = (const float*)d_in[26];
    const float* rho_w1  = (const float*)d_in[27];
    const float* rho_b1  = (const float*)d_in[28];
    const float* rho_w2  = (const float*)d_in[29];
    const float* rho_b2  = (const float*)d_in[30];
    float* out = (float*)d_out;

    float* ws   = (float*)d_ws;
    float* H    = ws;               // 262144
    float* H2   = ws + 262144;      // 262144
    float* hsum = ws + 524288;      // 2048
    float* asum = ws + 526336;      // 2048 (contiguous with hsum)
    unsigned* bar = (unsigned*)(ws + 528384);

    hipMemsetAsync(bar, 0, 2 * sizeof(unsigned), stream);
    k_mega<<<512, 256, 0, stream>>>(
        A, X, home_mask, emb1_w, emb1_b, emb2_w, emb2_b,
        rgcn_w0, rgcn_root0, rgcn_bias0, lina_w0, lina_b0, linb_w0, linb_b0,
        rgcn_w1, rgcn_root1, rgcn_bias1, lina_w1, lina_b1, linb_w1, linb_b1,
        norm_g, norm_b, phi_w1, phi_b1, phi_w2, phi_b2,
        rho_w1, rho_b1, rho_w2, rho_b2,
        H, H2, hsum, asum, out, bar);
}

// Round 2
// 195.687 us; speedup vs baseline: 2.5961x; 2.5961x over previous
//
#include <hip/hip_runtime.h>
#include <math.h>

// Shapes: B=8, N=256, NID=64, V=GH=128, PHI=256, RHO=128
#define NB 8

// ---------------------------------------------------------------------------
// k_embed: H = relu(X@w1+b1)@w2+b2. 4 rows/block, grid 512.
// Direct-from-L2 weight reads (no LDS staging). q=f-quad, u=k-slice of 8.
// ---------------------------------------------------------------------------
__global__ __launch_bounds__(256, 2) void k_embed(const float* __restrict__ X,
        const float* __restrict__ w1, const float* __restrict__ b1,
        const float* __restrict__ w2, const float* __restrict__ b2,
        float* __restrict__ H, float* __restrict__ pools) {
    const int r0 = blockIdx.x * 4;
    const int t = threadIdx.x, q = t & 31, u = t >> 5;
    __shared__ __align__(16) float part[4096];   // [u][r][128]
    __shared__ __align__(16) float xq[256];      // [k][r]
    __shared__ __align__(16) float h1q[512];     // [k][r]
    if (blockIdx.x < 16) pools[blockIdx.x * 256 + t] = 0.f;
    if (t < 64) {
        float4 v;
        v.x = X[(size_t)(r0 + 0) * 64 + t];
        v.y = X[(size_t)(r0 + 1) * 64 + t];
        v.z = X[(size_t)(r0 + 2) * 64 + t];
        v.w = X[(size_t)(r0 + 3) * 64 + t];
        *(float4*)&xq[t * 4] = v;
    }
    __syncthreads();
    {   // L1: K=64, thread covers k in [u*8, u*8+8)
        float acc[16];
        #pragma unroll
        for (int i = 0; i < 16; ++i) acc[i] = 0.f;
        #pragma unroll
        for (int kk = 0; kk < 8; ++kk) {
            int k = u * 8 + kk;
            float4 w4 = *(const float4*)&w1[(size_t)k * 128 + q * 4];
            float wc[4] = {w4.x, w4.y, w4.z, w4.w};
            float4 x4 = *(const float4*)&xq[k * 4];
            float xr[4] = {x4.x, x4.y, x4.z, x4.w};
            #pragma unroll
            for (int r = 0; r < 4; ++r)
                #pragma unroll
                for (int c = 0; c < 4; ++c)
                    acc[r * 4 + c] = fmaf(xr[r], wc[c], acc[r * 4 + c]);
        }
        #pragma unroll
        for (int r = 0; r < 4; ++r)
            *(float4*)&part[u * 512 + r * 128 + q * 4] =
                make_float4(acc[r*4+0], acc[r*4+1], acc[r*4+2], acc[r*4+3]);
    }
    __syncthreads();
    if (t < 128) {
        int r = t >> 5, fq = t & 31;
        float4 s = *(const float4*)&b1[fq * 4];
        #pragma unroll
        for (int uu = 0; uu < 8; ++uu) {
            float4 p = *(const float4*)&part[uu * 512 + r * 128 + fq * 4];
            s.x += p.x; s.y += p.y; s.z += p.z; s.w += p.w;
        }
        h1q[(fq * 4 + 0) * 4 + r] = fmaxf(s.x, 0.f);
        h1q[(fq * 4 + 1) * 4 + r] = fmaxf(s.y, 0.f);
        h1q[(fq * 4 + 2) * 4 + r] = fmaxf(s.z, 0.f);
        h1q[(fq * 4 + 3) * 4 + r] = fmaxf(s.w, 0.f);
    }
    __syncthreads();
    {   // L2: K=128, thread covers k in [u*16, u*16+16)
        float a2[16];
        #pragma unroll
        for (int i = 0; i < 16; ++i) a2[i] = 0.f;
        #pragma unroll 8
        for (int kk = 0; kk < 16; ++kk) {
            int k = u * 16 + kk;
            float4 w4 = *(const float4*)&w2[(size_t)k * 128 + q * 4];
            float wc[4] = {w4.x, w4.y, w4.z, w4.w};
            float4 h4 = *(const float4*)&h1q[k * 4];
            float hr[4] = {h4.x, h4.y, h4.z, h4.w};
            #pragma unroll
            for (int r = 0; r < 4; ++r)
                #pragma unroll
                for (int c = 0; c < 4; ++c)
                    a2[r * 4 + c] = fmaf(hr[r], wc[c], a2[r * 4 + c]);
        }
        #pragma unroll
        for (int r = 0; r < 4; ++r)
            *(float4*)&part[u * 512 + r * 128 + q * 4] =
                make_float4(a2[r*4+0], a2[r*4+1], a2[r*4+2], a2[r*4+3]);
    }
    __syncthreads();
    if (t < 128) {
        int r = t >> 5, fq = t & 31;
        float4 s = *(const float4*)&b2[fq * 4];
        #pragma unroll
        for (int uu = 0; uu < 8; ++uu) {
            float4 p = *(const float4*)&part[uu * 512 + r * 128 + fq * 4];
            s.x += p.x; s.y += p.y; s.z += p.z; s.w += p.w;
        }
        *(float4*)&H[(size_t)(r0 + r) * 128 + fq * 4] = s;
    }
}

// ---------------------------------------------------------------------------
// k_gcn1: relation-mean aggregation + RGCN 3-matrix linear, fused.
// Block = (b, 4 targets j). Phase A: H read direct from L2 (each element
// once per block), no tile barriers. Phase B: weights direct from L2.
// ---------------------------------------------------------------------------
__global__ __launch_bounds__(256, 2) void k_gcn1(
        const float* __restrict__ A, const float* __restrict__ H,
        const float* __restrict__ Wrel, const float* __restrict__ Wroot,
        const float* __restrict__ bias, float* __restrict__ H2) {
    const int b  = blockIdx.x >> 6;
    const int j0 = (blockIdx.x & 63) * 4;
    const int t = threadIdx.x, q = t & 31, u = t >> 5;
    __shared__ __align__(16) float maskM[2048];  // [256][8]
    __shared__ __align__(16) float part[8192];   // [8u][8slot][128]
    __shared__ __align__(16) float pb[1536];     // [k][h4|m0_4|m1_4]
    __shared__ float cntp[256];
    __shared__ float cnt[8];
    const float* Ab = A + (size_t)b * 65536;
    const float* Hb = H + (size_t)b * 32768;
    const float* W0 = Wrel;
    const float* W1 = Wrel + 16384;

    {   // masks: thread t owns row i=t
        float4 a = *(const float4*)(Ab + (size_t)t * 256 + j0);
        float4 m0, m1;
        m0.x = (a.x < 0.f) ? 1.f : 0.f; m1.x = (a.x > 0.f) ? 1.f : 0.f;
        m0.y = (a.y < 0.f) ? 1.f : 0.f; m1.y = (a.y > 0.f) ? 1.f : 0.f;
        m0.z = (a.z < 0.f) ? 1.f : 0.f; m1.z = (a.z > 0.f) ? 1.f : 0.f;
        m0.w = (a.w < 0.f) ? 1.f : 0.f; m1.w = (a.w > 0.f) ? 1.f : 0.f;
        *(float4*)&maskM[t * 8]     = m0;
        *(float4*)&maskM[t * 8 + 4] = m1;
    }
    __syncthreads();
    {   // count partials: 32 chunks x 8 slots
        int chunk = t >> 3, slot = t & 7;
        float c = 0.f;
        #pragma unroll
        for (int qq = 0; qq < 8; ++qq) c += maskM[(chunk * 8 + qq) * 8 + slot];
        cntp[slot * 32 + chunk] = c;
    }
    // phase A: thread sweeps i in [u*32, u*32+32), H direct from L2
    float acc0[16], acc1[16];
    #pragma unroll
    for (int i = 0; i < 16; ++i) { acc0[i] = 0.f; acc1[i] = 0.f; }
    #pragma unroll 8
    for (int ii = 0; ii < 32; ++ii) {
        int i = u * 32 + ii;
        float4 h4 = *(const float4*)&Hb[(size_t)i * 128 + q * 4];
        float hc[4] = {h4.x, h4.y, h4.z, h4.w};
        float4 m0 = *(const float4*)&maskM[i * 8];
        float4 m1 = *(const float4*)&maskM[i * 8 + 4];
        float mr0[4] = {m0.x, m0.y, m0.z, m0.w};
        float mr1[4] = {m1.x, m1.y, m1.z, m1.w};
        #pragma unroll
        for (int r = 0; r < 4; ++r)
            #pragma unroll
            for (int c = 0; c < 4; ++c) {
                acc0[r * 4 + c] = fmaf(mr0[r], hc[c], acc0[r * 4 + c]);
                acc1[r * 4 + c] = fmaf(mr1[r], hc[c], acc1[r * 4 + c]);
            }
    }
    #pragma unroll
    for (int r = 0; r < 4; ++r) {
        *(float4*)&part[u * 1024 + r * 128 + q * 4] =
            make_float4(acc0[r*4+0], acc0[r*4+1], acc0[r*4+2], acc0[r*4+3]);
        *(float4*)&part[u * 1024 + (4 + r) * 128 + q * 4] =
            make_float4(acc1[r*4+0], acc1[r*4+1], acc1[r*4+2], acc1[r*4+3]);
    }
    if (t < 8) {
        float s = 0.f;
        #pragma unroll
        for (int c = 0; c < 32; ++c) s += cntp[t * 32 + c];
        cnt[t] = s;
    }
    __syncthreads();
    {   // A-combine -> means into pb (slot = rel*4+r)
        int slot = t >> 5, fq = t & 31;
        float4 s = make_float4(0.f, 0.f, 0.f, 0.f);
        #pragma unroll
        for (int uu = 0; uu < 8; ++uu) {
            float4 p = *(const float4*)&part[uu * 1024 + slot * 128 + fq * 4];
            s.x += p.x; s.y += p.y; s.z += p.z; s.w += p.w;
        }
        float rc = 1.f / fmaxf(cnt[slot], 1.f);
        pb[(fq * 4 + 0) * 12 + 4 + slot] = s.x * rc;
        pb[(fq * 4 + 1) * 12 + 4 + slot] = s.y * rc;
        pb[(fq * 4 + 2) * 12 + 4 + slot] = s.z * rc;
        pb[(fq * 4 + 3) * 12 + 4 + slot] = s.w * rc;
    }
    if (t < 128) {  // root rows -> pb
        int r = t >> 5, fq = t & 31;
        float4 g4 = *(const float4*)(Hb + (size_t)(j0 + r) * 128 + fq * 4);
        pb[(fq * 4 + 0) * 12 + r] = g4.x;
        pb[(fq * 4 + 1) * 12 + r] = g4.y;
        pb[(fq * 4 + 2) * 12 + r] = g4.z;
        pb[(fq * 4 + 3) * 12 + r] = g4.w;
    }
    __syncthreads();
    // phase B: K=128, thread covers k in [u*16, u*16+16), weights direct
    float bcc[16];
    #pragma unroll
    for (int i = 0; i < 16; ++i) bcc[i] = 0.f;
    #pragma unroll 4
    for (int kk = 0; kk < 16; ++kk) {
        int k = u * 16 + kk;
        float4 wr = *(const float4*)&Wroot[(size_t)k * 128 + q * 4];
        float4 wa = *(const float4*)&W0[(size_t)k * 128 + q * 4];
        float4 wb = *(const float4*)&W1[(size_t)k * 128 + q * 4];
        float wrc[4] = {wr.x, wr.y, wr.z, wr.w};
        float wac[4] = {wa.x, wa.y, wa.z, wa.w};
        float wbc[4] = {wb.x, wb.y, wb.z, wb.w};
        float4 hv = *(const float4*)&pb[k * 12];
        float4 q0 = *(const float4*)&pb[k * 12 + 4];
        float4 q1 = *(const float4*)&pb[k * 12 + 8];
        float hr[4] = {hv.x, hv.y, hv.z, hv.w};
        float m0r[4] = {q0.x, q0.y, q0.z, q0.w};
        float m1r[4] = {q1.x, q1.y, q1.z, q1.w};
        #pragma unroll
        for (int r = 0; r < 4; ++r)
            #pragma unroll
            for (int c = 0; c < 4; ++c) {
                float v = bcc[r * 4 + c];
                v = fmaf(hr[r], wrc[c], v);
                v = fmaf(m0r[r], wac[c], v);
                v = fmaf(m1r[r], wbc[c], v);
                bcc[r * 4 + c] = v;
            }
    }
    #pragma unroll
    for (int r = 0; r < 4; ++r)
        *(float4*)&part[u * 512 + r * 128 + q * 4] =
            make_float4(bcc[r*4+0], bcc[r*4+1], bcc[r*4+2], bcc[r*4+3]);
    __syncthreads();
    if (t < 128) {
        int r = t >> 5, fq = t & 31;
        float4 s = *(const float4*)&bias[fq * 4];
        #pragma unroll
        for (int uu = 0; uu < 8; ++uu) {
            float4 p = *(const float4*)&part[uu * 512 + r * 128 + fq * 4];
            s.x += p.x; s.y += p.y; s.z += p.z; s.w += p.w;
        }
        *(float4*)&H2[(size_t)(b * 256 + j0 + r) * 128 + fq * 4] = s;
    }
}

// ---------------------------------------------------------------------------
// k_gcn2: |A|-aggregation + LayerNorm + 2-layer MLP + H-update, fused.
// H2 and weights read direct from L2; LDS only for reductions.
// ---------------------------------------------------------------------------
__global__ __launch_bounds__(256, 2) void k_gcn2(
        const float* __restrict__ A, const float* __restrict__ H2,
        const float* __restrict__ g, const float* __restrict__ bta,
        const float* __restrict__ law, const float* __restrict__ lab,
        const float* __restrict__ lbw, const float* __restrict__ lbb,
        float* __restrict__ H) {
    const int b  = blockIdx.x >> 6;
    const int i0 = (blockIdx.x & 63) * 4;
    const int t = threadIdx.x, q = t & 31, u = t >> 5;
    __shared__ __align__(16) float part[4096];   // [8u][4r][128]
    __shared__ __align__(16) float absA[1024];   // [256][4]
    __shared__ __align__(16) float xq[512];      // [k][r]
    __shared__ __align__(16) float uq[512];      // [k][r]
    __shared__ float red[16];
    __shared__ float mi[8];
    const float* Ab  = A + (size_t)b * 65536;
    const float* H2b = H2 + (size_t)b * 32768;

    {
        float4 av;
        av.x = fabsf(Ab[(size_t)(i0 + 0) * 256 + t]);
        av.y = fabsf(Ab[(size_t)(i0 + 1) * 256 + t]);
        av.z = fabsf(Ab[(size_t)(i0 + 2) * 256 + t]);
        av.w = fabsf(Ab[(size_t)(i0 + 3) * 256 + t]);
        *(float4*)&absA[t * 4] = av;
    }
    __syncthreads();
    // phase A: thread sweeps j in [u*32, u*32+32), H2 direct from L2
    float acc[16];
    #pragma unroll
    for (int i = 0; i < 16; ++i) acc[i] = 0.f;
    #pragma unroll 8
    for (int jj = 0; jj < 32; ++jj) {
        int j = u * 32 + jj;
        float4 h4 = *(const float4*)&H2b[(size_t)j * 128 + q * 4];
        float hc[4] = {h4.x, h4.y, h4.z, h4.w};
        float4 a4 = *(const float4*)&absA[j * 4];
        float ar[4] = {a4.x, a4.y, a4.z, a4.w};
        #pragma unroll
        for (int r = 0; r < 4; ++r)
            #pragma unroll
            for (int c = 0; c < 4; ++c)
                acc[r * 4 + c] = fmaf(ar[r], hc[c], acc[r * 4 + c]);
    }
    #pragma unroll
    for (int r = 0; r < 4; ++r)
        *(float4*)&part[u * 512 + r * 128 + q * 4] =
            make_float4(acc[r*4+0], acc[r*4+1], acc[r*4+2], acc[r*4+3]);
    __syncthreads();
    // combine + LN (f = t for t<128)
    float x[4] = {0.f, 0.f, 0.f, 0.f};
    if (t < 128) {
        const int wv2 = t >> 6;
        #pragma unroll
        for (int r = 0; r < 4; ++r) {
            float s = 0.f;
            #pragma unroll
            for (int uu = 0; uu < 8; ++uu) s += part[uu * 512 + r * 128 + t];
            x[r] = s;
        }
        #pragma unroll
        for (int r = 0; r < 4; ++r) {
            float s = x[r], s2 = x[r] * x[r];
            #pragma unroll
            for (int o = 32; o > 0; o >>= 1) {
                s  += __shfl_down(s, o, 64);
                s2 += __shfl_down(s2, o, 64);
            }
            if ((t & 63) == 0) {
                red[r * 4 + wv2 * 2] = s;
                red[r * 4 + wv2 * 2 + 1] = s2;
            }
        }
    }
    __syncthreads();
    if (t < 4) {
        float s  = red[t * 4] + red[t * 4 + 2];
        float s2 = red[t * 4 + 1] + red[t * 4 + 3];
        float m = s * (1.f / 128.f);
        float v = s2 * (1.f / 128.f) - m * m;
        mi[t * 2] = m;
        mi[t * 2 + 1] = rsqrtf(v + 1e-5f);
    }
    __syncthreads();
    if (t < 128) {
        float gf = g[t], bf = bta[t];
        float4 xv;
        xv.x = fmaxf((x[0] - mi[0]) * mi[1] * gf + bf, 0.f);
        xv.y = fmaxf((x[1] - mi[2]) * mi[3] * gf + bf, 0.f);
        xv.z = fmaxf((x[2] - mi[4]) * mi[5] * gf + bf, 0.f);
        xv.w = fmaxf((x[3] - mi[6]) * mi[7] * gf + bf, 0.f);
        *(float4*)&xq[t * 4] = xv;
    }
    __syncthreads();
    // MLP layer A: K=128, weights direct
    float u1[16];
    #pragma unroll
    for (int i = 0; i < 16; ++i) u1[i] = 0.f;
    #pragma unroll 8
    for (int kk = 0; kk < 16; ++kk) {
        int k = u * 16 + kk;
        float4 w4 = *(const float4*)&law[(size_t)k * 128 + q * 4];
        float wc[4] = {w4.x, w4.y, w4.z, w4.w};
        float4 x4 = *(const float4*)&xq[k * 4];
        float xr[4] = {x4.x, x4.y, x4.z, x4.w};
        #pragma unroll
        for (int r = 0; r < 4; ++r)
            #pragma unroll
            for (int c = 0; c < 4; ++c)
                u1[r * 4 + c] = fmaf(xr[r], wc[c], u1[r * 4 + c]);
    }
    #pragma unroll
    for (int r = 0; r < 4; ++r)
        *(float4*)&part[u * 512 + r * 128 + q * 4] =
            make_float4(u1[r*4+0], u1[r*4+1], u1[r*4+2], u1[r*4+3]);
    __syncthreads();
    if (t < 128) {
        float bb = lab[t];
        float4 uv;
        float s0 = 0.f, s1 = 0.f, s2 = 0.f, s3 = 0.f;
        #pragma unroll
        for (int uu = 0; uu < 8; ++uu) {
            s0 += part[uu * 512 + 0 * 128 + t];
            s1 += part[uu * 512 + 1 * 128 + t];
            s2 += part[uu * 512 + 2 * 128 + t];
            s3 += part[uu * 512 + 3 * 128 + t];
        }
        uv.x = fmaxf(s0 + bb, 0.f);
        uv.y = fmaxf(s1 + bb, 0.f);
        uv.z = fmaxf(s2 + bb, 0.f);
        uv.w = fmaxf(s3 + bb, 0.f);
        *(float4*)&uq[t * 4] = uv;
    }
    __syncthreads();
    // MLP layer B: K=128, weights direct
    float u2[16];
    #pragma unroll
    for (int i = 0; i < 16; ++i) u2[i] = 0.f;
    #pragma unroll 8
    for (int kk = 0; kk < 16; ++kk) {
        int k = u * 16 + kk;
        float4 w4 = *(const float4*)&lbw[(size_t)k * 128 + q * 4];
        float wc[4] = {w4.x, w4.y, w4.z, w4.w};
        float4 x4 = *(const float4*)&uq[k * 4];
        float xr[4] = {x4.x, x4.y, x4.z, x4.w};
        #pragma unroll
        for (int r = 0; r < 4; ++r)
            #pragma unroll
            for (int c = 0; c < 4; ++c)
                u2[r * 4 + c] = fmaf(xr[r], wc[c], u2[r * 4 + c]);
    }
    #pragma unroll
    for (int r = 0; r < 4; ++r)
        *(float4*)&part[u * 512 + r * 128 + q * 4] =
            make_float4(u2[r*4+0], u2[r*4+1], u2[r*4+2], u2[r*4+3]);
    __syncthreads();
    if (t < 128) {
        int r = t >> 5, fq = t & 31;
        float4 s = *(const float4*)&lbb[fq * 4];
        #pragma unroll
        for (int uu = 0; uu < 8; ++uu) {
            float4 p = *(const float4*)&part[uu * 512 + r * 128 + fq * 4];
            s.x += p.x; s.y += p.y; s.z += p.z; s.w += p.w;
        }
        float4 hold = *(const float4*)(H + (size_t)(b * 256 + i0 + r) * 128 + fq * 4);
        s.x += hold.x; s.y += hold.y; s.z += hold.z; s.w += hold.w;
        *(float4*)&H[(size_t)(b * 256 + i0 + r) * 128 + fq * 4] = s;
    }
}

// ---------------------------------------------------------------------------
// k_deepset: phi (128->256->256 relu) + masked pooling. 4 rows/block,
// grid 512 (2 blocks/CU). q = t&63 (f-quad of 256), u = t>>6 (k-slice of 4).
// Weights direct from L2.
// ---------------------------------------------------------------------------
__global__ __launch_bounds__(256, 2) void k_deepset(
        const float* __restrict__ H, const float* __restrict__ hm,
        const float* __restrict__ w1, const float* __restrict__ b1,
        const float* __restrict__ w2, const float* __restrict__ b2,
        float* __restrict__ hsum, float* __restrict__ asum) {
    const int r0 = blockIdx.x * 4;
    const int b  = blockIdx.x >> 6;
    const int t  = threadIdx.x, q = t & 63, u = t >> 6;
    __shared__ __align__(16) float part[4096];   // [4u][4r][256]
    __shared__ __align__(16) float ph2[1024];    // [r][256]
    __shared__ __align__(16) float hraw[512];    // [r][128]
    __shared__ float hmv[4];
    if (t < 128) {
        float4 g4 = *(const float4*)&H[(size_t)r0 * 128 + t * 4];
        *(float4*)&hraw[t * 4] = g4;
    }
    if (t < 4) hmv[t] = hm[r0 + t];
    __syncthreads();
    // L1: K=128, thread covers k in [u*32, u*32+32)
    float acc[16];
    #pragma unroll
    for (int i = 0; i < 16; ++i) acc[i] = 0.f;
    #pragma unroll 8
    for (int kk = 0; kk < 32; ++kk) {
        int k = u * 32 + kk;
        float4 w4 = *(const float4*)&w1[(size_t)k * 256 + q * 4];
        float wc[4] = {w4.x, w4.y, w4.z, w4.w};
        float hr[4];
        #pragma unroll
        for (int r = 0; r < 4; ++r) hr[r] = hraw[r * 128 + k];
        #pragma unroll
        for (int r = 0; r < 4; ++r)
            #pragma unroll
            for (int c = 0; c < 4; ++c)
                acc[r * 4 + c] = fmaf(hr[r], wc[c], acc[r * 4 + c]);
    }
    #pragma unroll
    for (int r = 0; r < 4; ++r)
        *(float4*)&part[u * 1024 + r * 256 + q * 4] =
            make_float4(acc[r*4+0], acc[r*4+1], acc[r*4+2], acc[r*4+3]);
    __syncthreads();
    {   // combine L1 -> ph2 (relu)
        int r = t >> 6, fq = t & 63;
        float4 s = *(const float4*)&b1[fq * 4];
        #pragma unroll
        for (int uu = 0; uu < 4; ++uu) {
            float4 p = *(const float4*)&part[uu * 1024 + r * 256 + fq * 4];
            s.x += p.x; s.y += p.y; s.z += p.z; s.w += p.w;
        }
        s.x = fmaxf(s.x, 0.f); s.y = fmaxf(s.y, 0.f);
        s.z = fmaxf(s.z, 0.f); s.w = fmaxf(s.w, 0.f);
        *(float4*)&ph2[r * 256 + fq * 4] = s;
    }
    __syncthreads();
    // L2: K=256, thread covers k in [u*64, u*64+64)
    float a2[16];
    #pragma unroll
    for (int i = 0; i < 16; ++i) a2[i] = 0.f;
    #pragma unroll 8
    for (int kk = 0; kk < 64; ++kk) {
        int k = u * 64 + kk;
        float4 w4 = *(const float4*)&w2[(size_t)k * 256 + q * 4];
        float wc[4] = {w4.x, w4.y, w4.z, w4.w};
        float pr[4];
        #pragma unroll
        for (int r = 0; r < 4; ++r) pr[r] = ph2[r * 256 + k];
        #pragma unroll
        for (int r = 0; r < 4; ++r)
            #pragma unroll
            for (int c = 0; c < 4; ++c)
                a2[r * 4 + c] = fmaf(pr[r], wc[c], a2[r * 4 + c]);
    }
    #pragma unroll
    for (int r = 0; r < 4; ++r)
        *(float4*)&part[u * 1024 + r * 256 + q * 4] =
            make_float4(a2[r*4+0], a2[r*4+1], a2[r*4+2], a2[r*4+3]);
    __syncthreads();
    {   // final combine + relu + masked pool (f = t)
        float bb = b2[t];
        float hp = 0.f, sp = 0.f;
        #pragma unroll
        for (int r = 0; r < 4; ++r) {
            float s = bb;
            #pragma unroll
            for (int uu = 0; uu < 4; ++uu) s += part[uu * 1024 + r * 256 + t];
            float p = fmaxf(s, 0.f);
            sp += p;
            hp = fmaf(p, hmv[r], hp);
        }
        atomicAdd(&hsum[b * 256 + t], hp);
        atomicAdd(&asum[b * 256 + t], sp - hp);
    }
}

// ---------------------------------------------------------------------------
// k_rho: out[b] = 0.5 + 0.5*tanh(rho(home)-rho(away)); b2 cancels.
// Weights direct from L2.
// ---------------------------------------------------------------------------
__global__ __launch_bounds__(256) void k_rho(const float* __restrict__ hsum,
        const float* __restrict__ asum,
        const float* __restrict__ w1, const float* __restrict__ b1,
        const float* __restrict__ w2, const float* __restrict__ b2,
        float* __restrict__ out) {
    const int bIdx = blockIdx.x;
    const int t = threadIdx.x, q = t & 31, u = t >> 5;
    __shared__ __align__(16) float part[2048];
    __shared__ __align__(16) float sv[512];
    __shared__ float wsv[2];
    sv[t] = hsum[bIdx * 256 + t];
    sv[256 + t] = asum[bIdx * 256 + t];
    __syncthreads();
    float aH[4] = {0.f, 0.f, 0.f, 0.f}, aA[4] = {0.f, 0.f, 0.f, 0.f};
    #pragma unroll 8
    for (int kk = 0; kk < 32; ++kk) {
        int k = u * 32 + kk;
        float4 w4 = *(const float4*)&w1[(size_t)k * 128 + q * 4];
        float sh = sv[k], sa = sv[256 + k];
        aH[0] = fmaf(sh, w4.x, aH[0]); aA[0] = fmaf(sa, w4.x, aA[0]);
        aH[1] = fmaf(sh, w4.y, aH[1]); aA[1] = fmaf(sa, w4.y, aA[1]);
        aH[2] = fmaf(sh, w4.z, aH[2]); aA[2] = fmaf(sa, w4.z, aA[2]);
        aH[3] = fmaf(sh, w4.w, aH[3]); aA[3] = fmaf(sa, w4.w, aA[3]);
    }
    *(float4*)&part[u * 256 + q * 4]       = make_float4(aH[0], aH[1], aH[2], aH[3]);
    *(float4*)&part[u * 256 + 128 + q * 4] = make_float4(aA[0], aA[1], aA[2], aA[3]);
    __syncthreads();
    if (t < 64) {
        int vec = t >> 5, fq = t & 31;
        float4 s = make_float4(0.f, 0.f, 0.f, 0.f);
        #pragma unroll
        for (int uu = 0; uu < 8; ++uu) {
            float4 p = *(const float4*)&part[uu * 256 + vec * 128 + fq * 4];
            s.x += p.x; s.y += p.y; s.z += p.z; s.w += p.w;
        }
        float4 bb = *(const float4*)&b1[fq * 4];
        float4 w2q = *(const float4*)&w2[fq * 4];
        float p = fmaxf(s.x + bb.x, 0.f) * w2q.x
                + fmaxf(s.y + bb.y, 0.f) * w2q.y
                + fmaxf(s.z + bb.z, 0.f) * w2q.z
                + fmaxf(s.w + bb.w, 0.f) * w2q.w;
        #pragma unroll
        for (int o = 16; o > 0; o >>= 1) p += __shfl_down(p, o, 32);
        if ((t & 31) == 0) wsv[vec] = p;
    }
    __syncthreads();
    if (t == 0) out[bIdx] = 0.5f + 0.5f * tanhf(wsv[0] - wsv[1]);
}

// ---------------------------------------------------------------------------
extern "C" void kernel_launch(void* const* d_in, const int* in_sizes, int n_in,
                              void* d_out, int out_size, void* d_ws, size_t ws_size,
                              hipStream_t stream) {
    const float* A         = (const float*)d_in[0];
    const float* X         = (const float*)d_in[1];
    const float* home_mask = (const float*)d_in[2];
    const float* emb1_w    = (const float*)d_in[3];
    const float* emb1_b    = (const float*)d_in[4];
    const float* emb2_w    = (const float*)d_in[5];
    const float* emb2_b    = (const float*)d_in[6];
    const float* rgcn_w[2]    = { (const float*)d_in[7],  (const float*)d_in[14] };
    const float* rgcn_root[2] = { (const float*)d_in[8],  (const float*)d_in[15] };
    const float* rgcn_bias[2] = { (const float*)d_in[9],  (const float*)d_in[16] };
    const float* lina_w[2]    = { (const float*)d_in[10], (const float*)d_in[17] };
    const float* lina_b[2]    = { (const float*)d_in[11], (const float*)d_in[18] };
    const float* linb_w[2]    = { (const float*)d_in[12], (const float*)d_in[19] };
    const float* linb_b[2]    = { (const float*)d_in[13], (const float*)d_in[20] };
    const float* norm_g  = (const float*)d_in[21];
    const float* norm_b  = (const float*)d_in[22];
    const float* phi_w1  = (const float*)d_in[23];
    const float* phi_b1  = (const float*)d_in[24];
    const float* phi_w2  = (const float*)d_in[25];
    const float* phi_b2  = (const float*)d_in[26];
    const float* rho_w1  = (const float*)d_in[27];
    const float* rho_b1  = (const float*)d_in[28];
    const float* rho_w2  = (const float*)d_in[29];
    const float* rho_b2  = (const float*)d_in[30];
    float* out = (float*)d_out;

    float* ws   = (float*)d_ws;
    float* H    = ws;               // 262144
    float* H2   = ws + 262144;      // 262144
    float* hsum = ws + 524288;      // 2048
    float* asum = ws + 526336;      // 2048 (contiguous with hsum)

    k_embed<<<512, 256, 0, stream>>>(X, emb1_w, emb1_b, emb2_w, emb2_b, H, hsum);

    for (int it = 0; it < 2; ++it) {
        k_gcn1<<<512, 256, 0, stream>>>(A, H, rgcn_w[it], rgcn_root[it],
                                        rgcn_bias[it], H2);
        k_gcn2<<<512, 256, 0, stream>>>(A, H2, norm_g, norm_b,
                                        lina_w[it], lina_b[it],
                                        linb_w[it], linb_b[it], H);
    }

    k_deepset<<<512, 256, 0, stream>>>(H, home_mask, phi_w1, phi_b1,
                                       phi_w2, phi_b2, hsum, asum);
    k_rho<<<NB, 256, 0, stream>>>(hsum, asum, rho_w1, rho_b1, rho_w2, rho_b2, out);
}

// Round 3
// 189.299 us; speedup vs baseline: 2.6837x; 1.0337x over previous
//
#include <hip/hip_runtime.h>
#include <math.h>

// Shapes: B=8, N=256, NID=64, V=GH=128, PHI=256, RHO=128
#define NB 8

// ---------------------------------------------------------------------------
// k_embed: H = relu(X@w1+b1)@w2+b2. 4 rows/block, grid 512, 512 threads.
// q = t&31 (f-quad of 128), u = t>>5 (K-slice of 16). Direct-from-L2 weights.
// ---------------------------------------------------------------------------
__global__ __launch_bounds__(512, 4) void k_embed(const float* __restrict__ X,
        const float* __restrict__ w1, const float* __restrict__ b1,
        const float* __restrict__ w2, const float* __restrict__ b2,
        float* __restrict__ H, float* __restrict__ pools) {
    const int r0 = blockIdx.x * 4;
    const int t = threadIdx.x, q = t & 31, u = t >> 5;
    __shared__ __align__(16) float part[8192];   // [16u][4r][128f]
    __shared__ __align__(16) float xq[256];      // [k][r]
    __shared__ __align__(16) float h1q[512];     // [k][r]
    if (blockIdx.x < 8) pools[blockIdx.x * 512 + t] = 0.f;
    if (t < 64) {
        float4 v;
        v.x = X[(size_t)(r0 + 0) * 64 + t];
        v.y = X[(size_t)(r0 + 1) * 64 + t];
        v.z = X[(size_t)(r0 + 2) * 64 + t];
        v.w = X[(size_t)(r0 + 3) * 64 + t];
        *(float4*)&xq[t * 4] = v;
    }
    __syncthreads();
    {   // L1: K=64, thread covers k in [u*4, u*4+4)
        float acc[16];
        #pragma unroll
        for (int i = 0; i < 16; ++i) acc[i] = 0.f;
        #pragma unroll
        for (int kk = 0; kk < 4; ++kk) {
            int k = u * 4 + kk;
            float4 w4 = *(const float4*)&w1[(size_t)k * 128 + q * 4];
            float wc[4] = {w4.x, w4.y, w4.z, w4.w};
            float4 x4 = *(const float4*)&xq[k * 4];
            float xr[4] = {x4.x, x4.y, x4.z, x4.w};
            #pragma unroll
            for (int r = 0; r < 4; ++r)
                #pragma unroll
                for (int c = 0; c < 4; ++c)
                    acc[r * 4 + c] = fmaf(xr[r], wc[c], acc[r * 4 + c]);
        }
        #pragma unroll
        for (int r = 0; r < 4; ++r)
            *(float4*)&part[u * 512 + r * 128 + q * 4] =
                make_float4(acc[r*4+0], acc[r*4+1], acc[r*4+2], acc[r*4+3]);
    }
    __syncthreads();
    {   // combine -> h1q: thread owns (r,f)
        int r = t >> 7, f = t & 127;
        float s = b1[f];
        #pragma unroll
        for (int uu = 0; uu < 16; ++uu) s += part[uu * 512 + r * 128 + f];
        h1q[f * 4 + r] = fmaxf(s, 0.f);
    }
    __syncthreads();
    {   // L2: K=128, thread covers k in [u*8, u*8+8)
        float a2[16];
        #pragma unroll
        for (int i = 0; i < 16; ++i) a2[i] = 0.f;
        #pragma unroll
        for (int kk = 0; kk < 8; ++kk) {
            int k = u * 8 + kk;
            float4 w4 = *(const float4*)&w2[(size_t)k * 128 + q * 4];
            float wc[4] = {w4.x, w4.y, w4.z, w4.w};
            float4 h4 = *(const float4*)&h1q[k * 4];
            float hr[4] = {h4.x, h4.y, h4.z, h4.w};
            #pragma unroll
            for (int r = 0; r < 4; ++r)
                #pragma unroll
                for (int c = 0; c < 4; ++c)
                    a2[r * 4 + c] = fmaf(hr[r], wc[c], a2[r * 4 + c]);
        }
        #pragma unroll
        for (int r = 0; r < 4; ++r)
            *(float4*)&part[u * 512 + r * 128 + q * 4] =
                make_float4(a2[r*4+0], a2[r*4+1], a2[r*4+2], a2[r*4+3]);
    }
    __syncthreads();
    {
        int r = t >> 7, f = t & 127;
        float s = b2[f];
        #pragma unroll
        for (int uu = 0; uu < 16; ++uu) s += part[uu * 512 + r * 128 + f];
        H[(size_t)(r0 + r) * 128 + f] = s;
    }
}

// ---------------------------------------------------------------------------
// k_gcn1: relation-mean aggregation + RGCN 3-matrix linear, fused.
// 512 threads; block = (b, 4 targets). Phase A i-slices of 16 per thread;
// two-pass rel combine keeps part at 32 KB. Weights direct from L2.
// ---------------------------------------------------------------------------
__global__ __launch_bounds__(512, 4) void k_gcn1(
        const float* __restrict__ A, const float* __restrict__ H,
        const float* __restrict__ Wrel, const float* __restrict__ Wroot,
        const float* __restrict__ bias, float* __restrict__ H2) {
    const int b  = blockIdx.x >> 6;
    const int j0 = (blockIdx.x & 63) * 4;
    const int t = threadIdx.x, q = t & 31, u = t >> 5;
    __shared__ __align__(16) float maskM[2048];  // [256][8]
    __shared__ __align__(16) float part[8192];   // [16u][4r][128f]
    __shared__ __align__(16) float pb[1536];     // [k][h4|m0_4|m1_4]
    __shared__ float cntp[256];
    __shared__ float cnt[8];
    const float* Ab = A + (size_t)b * 65536;
    const float* Hb = H + (size_t)b * 32768;
    const float* W0 = Wrel;
    const float* W1 = Wrel + 16384;

    if (t < 256) {   // masks: thread t owns row i=t
        float4 a = *(const float4*)(Ab + (size_t)t * 256 + j0);
        float4 m0, m1;
        m0.x = (a.x < 0.f) ? 1.f : 0.f; m1.x = (a.x > 0.f) ? 1.f : 0.f;
        m0.y = (a.y < 0.f) ? 1.f : 0.f; m1.y = (a.y > 0.f) ? 1.f : 0.f;
        m0.z = (a.z < 0.f) ? 1.f : 0.f; m1.z = (a.z > 0.f) ? 1.f : 0.f;
        m0.w = (a.w < 0.f) ? 1.f : 0.f; m1.w = (a.w > 0.f) ? 1.f : 0.f;
        *(float4*)&maskM[t * 8]     = m0;
        *(float4*)&maskM[t * 8 + 4] = m1;
    }
    __syncthreads();
    if (t < 256) {   // count partials: 32 chunks x 8 slots
        int chunk = t >> 3, slot = t & 7;
        float c = 0.f;
        #pragma unroll
        for (int qq = 0; qq < 8; ++qq) c += maskM[(chunk * 8 + qq) * 8 + slot];
        cntp[slot * 32 + chunk] = c;
    }
    // phase A: thread sweeps i in [u*16, u*16+16), H direct from L2
    float acc0[16], acc1[16];
    #pragma unroll
    for (int i = 0; i < 16; ++i) { acc0[i] = 0.f; acc1[i] = 0.f; }
    #pragma unroll 8
    for (int ii = 0; ii < 16; ++ii) {
        int i = u * 16 + ii;
        float4 h4 = *(const float4*)&Hb[(size_t)i * 128 + q * 4];
        float hc[4] = {h4.x, h4.y, h4.z, h4.w};
        float4 m0 = *(const float4*)&maskM[i * 8];
        float4 m1 = *(const float4*)&maskM[i * 8 + 4];
        float mr0[4] = {m0.x, m0.y, m0.z, m0.w};
        float mr1[4] = {m1.x, m1.y, m1.z, m1.w};
        #pragma unroll
        for (int r = 0; r < 4; ++r)
            #pragma unroll
            for (int c = 0; c < 4; ++c) {
                acc0[r * 4 + c] = fmaf(mr0[r], hc[c], acc0[r * 4 + c]);
                acc1[r * 4 + c] = fmaf(mr1[r], hc[c], acc1[r * 4 + c]);
            }
    }
    // pass 1: rel0
    #pragma unroll
    for (int r = 0; r < 4; ++r)
        *(float4*)&part[u * 512 + r * 128 + q * 4] =
            make_float4(acc0[r*4+0], acc0[r*4+1], acc0[r*4+2], acc0[r*4+3]);
    if (t < 8) {
        float s = 0.f;
        #pragma unroll
        for (int c = 0; c < 32; ++c) s += cntp[t * 32 + c];
        cnt[t] = s;
    }
    __syncthreads();
    {
        int r = t >> 7, f = t & 127;
        float s = 0.f;
        #pragma unroll
        for (int uu = 0; uu < 16; ++uu) s += part[uu * 512 + r * 128 + f];
        pb[f * 12 + 4 + r] = s * (1.f / fmaxf(cnt[r], 1.f));
    }
    __syncthreads();
    // pass 2: rel1 + root rows
    #pragma unroll
    for (int r = 0; r < 4; ++r)
        *(float4*)&part[u * 512 + r * 128 + q * 4] =
            make_float4(acc1[r*4+0], acc1[r*4+1], acc1[r*4+2], acc1[r*4+3]);
    __syncthreads();
    {
        int r = t >> 7, f = t & 127;
        float s = 0.f;
        #pragma unroll
        for (int uu = 0; uu < 16; ++uu) s += part[uu * 512 + r * 128 + f];
        pb[f * 12 + 8 + r] = s * (1.f / fmaxf(cnt[4 + r], 1.f));
    }
    if (t < 128) {  // root rows -> pb
        int r = t >> 5, fq = t & 31;
        float4 g4 = *(const float4*)(Hb + (size_t)(j0 + r) * 128 + fq * 4);
        pb[(fq * 4 + 0) * 12 + r] = g4.x;
        pb[(fq * 4 + 1) * 12 + r] = g4.y;
        pb[(fq * 4 + 2) * 12 + r] = g4.z;
        pb[(fq * 4 + 3) * 12 + r] = g4.w;
    }
    __syncthreads();
    // phase B: K=128, thread covers k in [u*8, u*8+8), weights direct
    float bcc[16];
    #pragma unroll
    for (int i = 0; i < 16; ++i) bcc[i] = 0.f;
    #pragma unroll 4
    for (int kk = 0; kk < 8; ++kk) {
        int k = u * 8 + kk;
        float4 wr = *(const float4*)&Wroot[(size_t)k * 128 + q * 4];
        float4 wa = *(const float4*)&W0[(size_t)k * 128 + q * 4];
        float4 wb = *(const float4*)&W1[(size_t)k * 128 + q * 4];
        float wrc[4] = {wr.x, wr.y, wr.z, wr.w};
        float wac[4] = {wa.x, wa.y, wa.z, wa.w};
        float wbc[4] = {wb.x, wb.y, wb.z, wb.w};
        float4 hv = *(const float4*)&pb[k * 12];
        float4 q0 = *(const float4*)&pb[k * 12 + 4];
        float4 q1 = *(const float4*)&pb[k * 12 + 8];
        float hr[4] = {hv.x, hv.y, hv.z, hv.w};
        float m0r[4] = {q0.x, q0.y, q0.z, q0.w};
        float m1r[4] = {q1.x, q1.y, q1.z, q1.w};
        #pragma unroll
        for (int r = 0; r < 4; ++r)
            #pragma unroll
            for (int c = 0; c < 4; ++c) {
                float v = bcc[r * 4 + c];
                v = fmaf(hr[r], wrc[c], v);
                v = fmaf(m0r[r], wac[c], v);
                v = fmaf(m1r[r], wbc[c], v);
                bcc[r * 4 + c] = v;
            }
    }
    #pragma unroll
    for (int r = 0; r < 4; ++r)
        *(float4*)&part[u * 512 + r * 128 + q * 4] =
            make_float4(bcc[r*4+0], bcc[r*4+1], bcc[r*4+2], bcc[r*4+3]);
    __syncthreads();
    {
        int r = t >> 7, f = t & 127;
        float s = bias[f];
        #pragma unroll
        for (int uu = 0; uu < 16; ++uu) s += part[uu * 512 + r * 128 + f];
        H2[(size_t)(b * 256 + j0 + r) * 128 + f] = s;
    }
}

// ---------------------------------------------------------------------------
// k_gcn2: |A|-aggregation + LayerNorm + 2-layer MLP + H-update, fused.
// 512 threads; H2/weights direct from L2; LDS only for reductions.
// ---------------------------------------------------------------------------
__global__ __launch_bounds__(512, 4) void k_gcn2(
        const float* __restrict__ A, const float* __restrict__ H2,
        const float* __restrict__ g, const float* __restrict__ bta,
        const float* __restrict__ law, const float* __restrict__ lab,
        const float* __restrict__ lbw, const float* __restrict__ lbb,
        float* __restrict__ H) {
    const int b  = blockIdx.x >> 6;
    const int i0 = (blockIdx.x & 63) * 4;
    const int t = threadIdx.x, q = t & 31, u = t >> 5;
    __shared__ __align__(16) float part[8192];   // [16u][4r][128f]
    __shared__ __align__(16) float absA[1024];   // [256][4]
    __shared__ __align__(16) float xq[512];      // [k][r]
    __shared__ __align__(16) float uq[512];      // [k][r]
    __shared__ float red[16];
    __shared__ float mi[8];
    const float* Ab  = A + (size_t)b * 65536;
    const float* H2b = H2 + (size_t)b * 32768;

    if (t < 256) {
        float4 av;
        av.x = fabsf(Ab[(size_t)(i0 + 0) * 256 + t]);
        av.y = fabsf(Ab[(size_t)(i0 + 1) * 256 + t]);
        av.z = fabsf(Ab[(size_t)(i0 + 2) * 256 + t]);
        av.w = fabsf(Ab[(size_t)(i0 + 3) * 256 + t]);
        *(float4*)&absA[t * 4] = av;
    }
    __syncthreads();
    // phase A: thread sweeps j in [u*16, u*16+16)
    float acc[16];
    #pragma unroll
    for (int i = 0; i < 16; ++i) acc[i] = 0.f;
    #pragma unroll 8
    for (int jj = 0; jj < 16; ++jj) {
        int j = u * 16 + jj;
        float4 h4 = *(const float4*)&H2b[(size_t)j * 128 + q * 4];
        float hc[4] = {h4.x, h4.y, h4.z, h4.w};
        float4 a4 = *(const float4*)&absA[j * 4];
        float ar[4] = {a4.x, a4.y, a4.z, a4.w};
        #pragma unroll
        for (int r = 0; r < 4; ++r)
            #pragma unroll
            for (int c = 0; c < 4; ++c)
                acc[r * 4 + c] = fmaf(ar[r], hc[c], acc[r * 4 + c]);
    }
    #pragma unroll
    for (int r = 0; r < 4; ++r)
        *(float4*)&part[u * 512 + r * 128 + q * 4] =
            make_float4(acc[r*4+0], acc[r*4+1], acc[r*4+2], acc[r*4+3]);
    __syncthreads();
    // combine + LN: thread owns (r,f); row r = waves 2r,2r+1
    const int rr = t >> 7, ff = t & 127;
    float x;
    {
        float s = 0.f;
        #pragma unroll
        for (int uu = 0; uu < 16; ++uu) s += part[uu * 512 + rr * 128 + ff];
        x = s;
        float s2 = x * x;
        float sw = x;
        #pragma unroll
        for (int o = 32; o > 0; o >>= 1) {
            sw += __shfl_down(sw, o, 64);
            s2 += __shfl_down(s2, o, 64);
        }
        int w = (t >> 6) & 1;
        if ((t & 63) == 0) {
            red[(rr * 2 + w) * 2]     = sw;
            red[(rr * 2 + w) * 2 + 1] = s2;
        }
    }
    __syncthreads();
    if (t < 4) {
        float s  = red[t * 4]     + red[t * 4 + 2];
        float s2 = red[t * 4 + 1] + red[t * 4 + 3];
        float m = s * (1.f / 128.f);
        float v = s2 * (1.f / 128.f) - m * m;
        mi[t * 2] = m;
        mi[t * 2 + 1] = rsqrtf(v + 1e-5f);
    }
    __syncthreads();
    xq[ff * 4 + rr] = fmaxf((x - mi[rr * 2]) * mi[rr * 2 + 1] * g[ff] + bta[ff], 0.f);
    __syncthreads();
    // MLP layer A: K=128, thread covers k in [u*8, u*8+8)
    float u1[16];
    #pragma unroll
    for (int i = 0; i < 16; ++i) u1[i] = 0.f;
    #pragma unroll
    for (int kk = 0; kk < 8; ++kk) {
        int k = u * 8 + kk;
        float4 w4 = *(const float4*)&law[(size_t)k * 128 + q * 4];
        float wc[4] = {w4.x, w4.y, w4.z, w4.w};
        float4 x4 = *(const float4*)&xq[k * 4];
        float xr[4] = {x4.x, x4.y, x4.z, x4.w};
        #pragma unroll
        for (int r = 0; r < 4; ++r)
            #pragma unroll
            for (int c = 0; c < 4; ++c)
                u1[r * 4 + c] = fmaf(xr[r], wc[c], u1[r * 4 + c]);
    }
    #pragma unroll
    for (int r = 0; r < 4; ++r)
        *(float4*)&part[u * 512 + r * 128 + q * 4] =
            make_float4(u1[r*4+0], u1[r*4+1], u1[r*4+2], u1[r*4+3]);
    __syncthreads();
    {
        float s = lab[ff];
        #pragma unroll
        for (int uu = 0; uu < 16; ++uu) s += part[uu * 512 + rr * 128 + ff];
        uq[ff * 4 + rr] = fmaxf(s, 0.f);
    }
    __syncthreads();
    // MLP layer B: K=128
    float u2[16];
    #pragma unroll
    for (int i = 0; i < 16; ++i) u2[i] = 0.f;
    #pragma unroll
    for (int kk = 0; kk < 8; ++kk) {
        int k = u * 8 + kk;
        float4 w4 = *(const float4*)&lbw[(size_t)k * 128 + q * 4];
        float wc[4] = {w4.x, w4.y, w4.z, w4.w};
        float4 x4 = *(const float4*)&uq[k * 4];
        float xr[4] = {x4.x, x4.y, x4.z, x4.w};
        #pragma unroll
        for (int r = 0; r < 4; ++r)
            #pragma unroll
            for (int c = 0; c < 4; ++c)
                u2[r * 4 + c] = fmaf(xr[r], wc[c], u2[r * 4 + c]);
    }
    #pragma unroll
    for (int r = 0; r < 4; ++r)
        *(float4*)&part[u * 512 + r * 128 + q * 4] =
            make_float4(u2[r*4+0], u2[r*4+1], u2[r*4+2], u2[r*4+3]);
    __syncthreads();
    {
        float s = lbb[ff];
        #pragma unroll
        for (int uu = 0; uu < 16; ++uu) s += part[uu * 512 + rr * 128 + ff];
        size_t idx = (size_t)(b * 256 + i0 + rr) * 128 + ff;
        H[idx] = s + H[idx];
    }
}

// ---------------------------------------------------------------------------
// k_deepset: phi (128->256->256 relu) + masked pooling. 4 rows/block,
// grid 512, 512 threads. q = t&63 (f-quad of 256), u = t>>6 (K-slice of 8).
// ---------------------------------------------------------------------------
__global__ __launch_bounds__(512, 4) void k_deepset(
        const float* __restrict__ H, const float* __restrict__ hm,
        const float* __restrict__ w1, const float* __restrict__ b1,
        const float* __restrict__ w2, const float* __restrict__ b2,
        float* __restrict__ hsum, float* __restrict__ asum) {
    const int r0 = blockIdx.x * 4;
    const int b  = blockIdx.x >> 6;
    const int t  = threadIdx.x, q = t & 63, u = t >> 6;
    __shared__ __align__(16) float part[8192];   // [8u][4r][256f]
    __shared__ __align__(16) float ph2[1024];    // [r][256]
    __shared__ __align__(16) float hraw[512];    // [r][128]
    __shared__ float hmv[4];
    if (t < 128) {
        float4 g4 = *(const float4*)&H[(size_t)r0 * 128 + t * 4];
        *(float4*)&hraw[t * 4] = g4;
    }
    if (t < 4) hmv[t] = hm[r0 + t];
    __syncthreads();
    // L1: K=128, thread covers k in [u*16, u*16+16)
    float acc[16];
    #pragma unroll
    for (int i = 0; i < 16; ++i) acc[i] = 0.f;
    #pragma unroll 8
    for (int kk = 0; kk < 16; ++kk) {
        int k = u * 16 + kk;
        float4 w4 = *(const float4*)&w1[(size_t)k * 256 + q * 4];
        float wc[4] = {w4.x, w4.y, w4.z, w4.w};
        float hr[4];
        #pragma unroll
        for (int r = 0; r < 4; ++r) hr[r] = hraw[r * 128 + k];
        #pragma unroll
        for (int r = 0; r < 4; ++r)
            #pragma unroll
            for (int c = 0; c < 4; ++c)
                acc[r * 4 + c] = fmaf(hr[r], wc[c], acc[r * 4 + c]);
    }
    #pragma unroll
    for (int r = 0; r < 4; ++r)
        *(float4*)&part[u * 1024 + r * 256 + q * 4] =
            make_float4(acc[r*4+0], acc[r*4+1], acc[r*4+2], acc[r*4+3]);
    __syncthreads();
    {   // combine L1 -> ph2 (relu): 1024 outputs, 2 per thread
        #pragma unroll
        for (int e = 0; e < 2; ++e) {
            int idx = e * 512 + t;
            int r = idx >> 8, f = idx & 255;
            float s = b1[f];
            #pragma unroll
            for (int uu = 0; uu < 8; ++uu) s += part[uu * 1024 + r * 256 + f];
            ph2[r * 256 + f] = fmaxf(s, 0.f);
        }
    }
    __syncthreads();
    // L2: K=256, thread covers k in [u*32, u*32+32)
    float a2[16];
    #pragma unroll
    for (int i = 0; i < 16; ++i) a2[i] = 0.f;
    #pragma unroll 8
    for (int kk = 0; kk < 32; ++kk) {
        int k = u * 32 + kk;
        float4 w4 = *(const float4*)&w2[(size_t)k * 256 + q * 4];
        float wc[4] = {w4.x, w4.y, w4.z, w4.w};
        float pr[4];
        #pragma unroll
        for (int r = 0; r < 4; ++r) pr[r] = ph2[r * 256 + k];
        #pragma unroll
        for (int r = 0; r < 4; ++r)
            #pragma unroll
            for (int c = 0; c < 4; ++c)
                a2[r * 4 + c] = fmaf(pr[r], wc[c], a2[r * 4 + c]);
    }
    #pragma unroll
    for (int r = 0; r < 4; ++r)
        *(float4*)&part[u * 1024 + r * 256 + q * 4] =
            make_float4(a2[r*4+0], a2[r*4+1], a2[r*4+2], a2[r*4+3]);
    __syncthreads();
    if (t < 256) {   // final combine + relu + masked pool (f = t)
        float bb = b2[t];
        float hp = 0.f, sp = 0.f;
        #pragma unroll
        for (int r = 0; r < 4; ++r) {
            float s = bb;
            #pragma unroll
            for (int uu = 0; uu < 8; ++uu) s += part[uu * 1024 + r * 256 + t];
            float p = fmaxf(s, 0.f);
            sp += p;
            hp = fmaf(p, hmv[r], hp);
        }
        atomicAdd(&hsum[b * 256 + t], hp);
        atomicAdd(&asum[b * 256 + t], sp - hp);
    }
}

// ---------------------------------------------------------------------------
// k_rho: out[b] = 0.5 + 0.5*tanh(rho(home)-rho(away)); b2 cancels.
// ---------------------------------------------------------------------------
__global__ __launch_bounds__(256) void k_rho(const float* __restrict__ hsum,
        const float* __restrict__ asum,
        const float* __restrict__ w1, const float* __restrict__ b1,
        const float* __restrict__ w2, const float* __restrict__ b2,
        float* __restrict__ out) {
    const int bIdx = blockIdx.x;
    const int t = threadIdx.x, q = t & 31, u = t >> 5;
    __shared__ __align__(16) float part[2048];
    __shared__ __align__(16) float sv[512];
    __shared__ float wsv[2];
    sv[t] = hsum[bIdx * 256 + t];
    sv[256 + t] = asum[bIdx * 256 + t];
    __syncthreads();
    float aH[4] = {0.f, 0.f, 0.f, 0.f}, aA[4] = {0.f, 0.f, 0.f, 0.f};
    #pragma unroll 8
    for (int kk = 0; kk < 32; ++kk) {
        int k = u * 32 + kk;
        float4 w4 = *(const float4*)&w1[(size_t)k * 128 + q * 4];
        float sh = sv[k], sa = sv[256 + k];
        aH[0] = fmaf(sh, w4.x, aH[0]); aA[0] = fmaf(sa, w4.x, aA[0]);
        aH[1] = fmaf(sh, w4.y, aH[1]); aA[1] = fmaf(sa, w4.y, aA[1]);
        aH[2] = fmaf(sh, w4.z, aH[2]); aA[2] = fmaf(sa, w4.z, aA[2]);
        aH[3] = fmaf(sh, w4.w, aH[3]); aA[3] = fmaf(sa, w4.w, aA[3]);
    }
    *(float4*)&part[u * 256 + q * 4]       = make_float4(aH[0], aH[1], aH[2], aH[3]);
    *(float4*)&part[u * 256 + 128 + q * 4] = make_float4(aA[0], aA[1], aA[2], aA[3]);
    __syncthreads();
    if (t < 64) {
        int vec = t >> 5, fq = t & 31;
        float4 s = make_float4(0.f, 0.f, 0.f, 0.f);
        #pragma unroll
        for (int uu = 0; uu < 8; ++uu) {
            float4 p = *(const float4*)&part[uu * 256 + vec * 128 + fq * 4];
            s.x += p.x; s.y += p.y; s.z += p.z; s.w += p.w;
        }
        float4 bb = *(const float4*)&b1[fq * 4];
        float4 w2q = *(const float4*)&w2[fq * 4];
        float p = fmaxf(s.x + bb.x, 0.f) * w2q.x
                + fmaxf(s.y + bb.y, 0.f) * w2q.y
                + fmaxf(s.z + bb.z, 0.f) * w2q.z
                + fmaxf(s.w + bb.w, 0.f) * w2q.w;
        #pragma unroll
        for (int o = 16; o > 0; o >>= 1) p += __shfl_down(p, o, 32);
        if ((t & 31) == 0) wsv[vec] = p;
    }
    __syncthreads();
    if (t == 0) out[bIdx] = 0.5f + 0.5f * tanhf(wsv[0] - wsv[1]);
}

// ---------------------------------------------------------------------------
extern "C" void kernel_launch(void* const* d_in, const int* in_sizes, int n_in,
                              void* d_out, int out_size, void* d_ws, size_t ws_size,
                              hipStream_t stream) {
    const float* A         = (const float*)d_in[0];
    const float* X         = (const float*)d_in[1];
    const float* home_mask = (const float*)d_in[2];
    const float* emb1_w    = (const float*)d_in[3];
    const float* emb1_b    = (const float*)d_in[4];
    const float* emb2_w    = (const float*)d_in[5];
    const float* emb2_b    = (const float*)d_in[6];
    const float* rgcn_w[2]    = { (const float*)d_in[7],  (const float*)d_in[14] };
    const float* rgcn_root[2] = { (const float*)d_in[8],  (const float*)d_in[15] };
    const float* rgcn_bias[2] = { (const float*)d_in[9],  (const float*)d_in[16] };
    const float* lina_w[2]    = { (const float*)d_in[10], (const float*)d_in[17] };
    const float* lina_b[2]    = { (const float*)d_in[11], (const float*)d_in[18] };
    const float* linb_w[2]    = { (const float*)d_in[12], (const float*)d_in[19] };
    const float* linb_b[2]    = { (const float*)d_in[13], (const float*)d_in[20] };
    const float* norm_g  = (const float*)d_in[21];
    const float* norm_b  = (const float*)d_in[22];
    const float* phi_w1  = (const float*)d_in[23];
    const float* phi_b1  = (const float*)d_in[24];
    const float* phi_w2  = (const float*)d_in[25];
    const float* phi_b2  = (const float*)d_in[26];
    const float* rho_w1  = (const float*)d_in[27];
    const float* rho_b1  = (const float*)d_in[28];
    const float* rho_w2  = (const float*)d_in[29];
    const float* rho_b2  = (const float*)d_in[30];
    float* out = (float*)d_out;

    float* ws   = (float*)d_ws;
    float* H    = ws;               // 262144
    float* H2   = ws + 262144;      // 262144
    float* hsum = ws + 524288;      // 2048
    float* asum = ws + 526336;      // 2048 (contiguous with hsum)

    k_embed<<<512, 512, 0, stream>>>(X, emb1_w, emb1_b, emb2_w, emb2_b, H, hsum);

    for (int it = 0; it < 2; ++it) {
        k_gcn1<<<512, 512, 0, stream>>>(A, H, rgcn_w[it], rgcn_root[it],
                                        rgcn_bias[it], H2);
        k_gcn2<<<512, 512, 0, stream>>>(A, H2, norm_g, norm_b,
                                        lina_w[it], lina_b[it],
                                        linb_w[it], linb_b[it], H);
    }

    k_deepset<<<512, 512, 0, stream>>>(H, home_mask, phi_w1, phi_b1,
                                       phi_w2, phi_b2, hsum, asum);
    k_rho<<<NB, 256, 0, stream>>>(hsum, asum, rho_w1, rho_b1, rho_w2, rho_b2, out);
}